// Round 10
// baseline (401.292 us; speedup 1.0000x reference)
//
#include <hip/hip_runtime.h>
#include <stdint.h>

typedef short bf16x8 __attribute__((ext_vector_type(8)));
typedef float f32x4 __attribute__((ext_vector_type(4)));
typedef unsigned short u16;
typedef unsigned long long u64;

#define B_  32
#define S_  64
#define V_  32000
#define H_  512
#define T_  63
#define R_  2016
#define RP_ 2048
#define G3_ 1536
#define NWG 32
#define NWORK 128

// ---- workspace offsets (bytes), all 1KB aligned ----
#define o_X      0ull          // X bf16 [2048][1024]
#define o_Wih    4194304ull    // w_ih_w bf16 [1536][1024]
#define o_OutW   7340032ull    // out_w bf16 [32000][512]
#define o_PackHH 40108032ull   // packed w_hh_w frags
#define o_PackIS 41680896ull   // packed w_ih_s frags
#define o_PackHS 43253760ull   // packed w_hh_s frags
#define o_GI     44826624ull   // gi fp32 [2016][1536]
#define o_WHf    57212928ull   // word_h fp32 [2016][512]
#define o_WHb    61341696ull   // word_h bf16 pre-swizzled [2048][512]
#define o_HPUB   63438848ull   // published h bf16 (chunk-swizzled) [2][4096] u64
#define o_SPUB   63504384ull   // published sent_h [2][4096] u64
#define o_ARR    63569920ull   // EOS-path arrival counters int[256]
#define o_CTR    63571968ull   // [32]=steps_done
#define o_PART   63733760ull   // partials float2 [2048][512]
#define o_LSE    72122368ull   // lse fp32 [2016]
#define o_RL     72130560ull   // rowloss fp32 [2048]
#define o_FLG    72138752ull   // eos flags int[64]
#define o_HFLG   72139776ull   // per-WG step flags int[32*16] (64B apart)

__device__ __forceinline__ u16 f2b(float f) {
  unsigned u = __float_as_uint(f);
  u = (u + 0x7FFFu + ((u >> 16) & 1u)) >> 16;
  return (u16)u;
}
__device__ __forceinline__ float sigm(float x) { return 1.0f / (1.0f + __expf(-x)); }

// ---- EOS-path central barrier (rare) ----
__device__ __forceinline__ void fbar(int* arr, int ph, int tid) {
  __syncthreads();
  if (tid == 0) {
    __hip_atomic_fetch_add(&arr[ph], 1, __ATOMIC_RELAXED, __HIP_MEMORY_SCOPE_AGENT);
    while (__hip_atomic_load(&arr[ph], __ATOMIC_RELAXED, __HIP_MEMORY_SCOPE_AGENT) < NWG)
      __builtin_amdgcn_s_sleep(1);
  }
  __syncthreads();
}

// ================= fused prologue: gather | init | cvt(wih) | pack x3 | out-zero =================
__global__ __launch_bounds__(256) void k_prep(
    const float* __restrict__ emb, const int* __restrict__ tg, const int* __restrict__ tk,
    u16* __restrict__ X, const float* __restrict__ sent, u64* __restrict__ hpub,
    u64* __restrict__ spub, u16* __restrict__ whb, int* __restrict__ flg, int* __restrict__ arr,
    int* __restrict__ ctr, int* __restrict__ hflg, const float* __restrict__ wihw,
    u16* __restrict__ wih16, const float* __restrict__ whhw, u16* __restrict__ packHH,
    const float* __restrict__ wihs, u16* __restrict__ packIS, const float* __restrict__ whhs,
    u16* __restrict__ packHS, float* __restrict__ out) {
  const int bid = blockIdx.x;
  const int tid = threadIdx.x;
  if (bid < 2048) {
    // ---- gather X = [emb[kw] | emb[lw]] bf16, pad rows zero ----
    int r = bid;
    u16* xr = X + (size_t)r * 1024;
    if (r < R_) {
      int t = r >> 5, b = r & 31;
      int kw = tk[b * 64 + t + 1];
      int lw = tg[b * 64 + t];
      const float* src = (tid < 128) ? (emb + (size_t)kw * 512 + tid * 4)
                                     : (emb + (size_t)lw * 512 + (tid - 128) * 4);
      float4 v = *(const float4*)src;
      u16 o[4] = {f2b(v.x), f2b(v.y), f2b(v.z), f2b(v.w)};
      *(uint2*)(xr + tid * 4) = *(uint2*)o;
    } else {
      u16 z[4] = {0, 0, 0, 0};
      *(uint2*)(xr + tid * 4) = *(uint2*)z;
    }
  } else if (bid < 2112) {
    // ---- init: Hpub[0]/Spub[0], whb pad, flags, counters, out zero ----
    int lb = bid - 2048;
    int idx = lb * 256 + tid;  // < 16384
    whb[(size_t)R_ * 512 + idx] = 0;
    if (idx < 2048) {  // chunk (b, c): 8 bf16 at slot c^(b&7)
      int b = idx >> 6, c = idx & 63;
      const float* p = sent + (size_t)b * 512 + c * 8;
      float4 v0 = *(const float4*)p;
      float4 v1 = *(const float4*)(p + 4);
      u16 t[8] = {f2b(v0.x), f2b(v0.y), f2b(v0.z), f2b(v0.w),
                  f2b(v1.x), f2b(v1.y), f2b(v1.z), f2b(v1.w)};
      int slot = c ^ (b & 7);
      u64* d = hpub + b * 128 + slot * 2;
      d[0] = ((const u64*)t)[0];
      d[1] = ((const u64*)t)[1];
      u64* s = spub + b * 128 + slot * 2;
      s[0] = ((const u64*)t)[0];
      s[1] = ((const u64*)t)[1];
    }
    if (lb == 0 && tid < 63) {
      int f = 0;
      for (int b = 0; b < 32; ++b) f |= (tg[b * 64 + tid + 1] == 1);
      flg[tid] = f;
    }
    if (lb == 1) arr[tid] = 0;
    if (lb == 2) ctr[tid] = 0;
    if (lb == 3) hflg[tid] = 0;
    if (lb == 4) hflg[256 + tid] = 0;
    if (lb == 5 && tid == 0) out[0] = 0.f;
  } else if (bid < 3648) {
    // ---- f32 -> bf16 rowmajor convert: w_ih_w ----
    int i4 = ((bid - 2112) * 256 + tid) * 4;
    if (i4 < G3_ * 1024) {
      float4 v = *(const float4*)(wihw + i4);
      u16 t[4] = {f2b(v.x), f2b(v.y), f2b(v.z), f2b(v.w)};
      *(uint2*)(wih16 + i4) = *(uint2*)t;
    }
  } else {
    // ---- pack [1536][512] f32 weight into bf16 MFMA B-fragment order ----
    int pb = bid - 3648;  // 0..1151
    const float* w;
    u16* up;
    int lb;
    if (pb < 384) { w = whhw; up = packHH; lb = pb; }
    else if (pb < 768) { w = wihs; up = packIS; lb = pb - 384; }
    else { w = whhs; up = packHS; lb = pb - 768; }
    int uid = lb * 256 + tid;  // < 98304
    int lane = uid & 63;
    int ksct = uid >> 6;
    int ks = ksct & 15, ct = ksct >> 4;
    int nrow = ct * 16 + (lane & 15);
    int k0 = ks * 32 + (lane >> 4) * 8;
    const float* p = w + (size_t)nrow * 512 + k0;
    float4 v0 = *(const float4*)p;
    float4 v1 = *(const float4*)(p + 4);
    u16 t[8] = {f2b(v0.x), f2b(v0.y), f2b(v0.z), f2b(v0.w),
                f2b(v1.x), f2b(v1.y), f2b(v1.z), f2b(v1.w)};
    *(uint4*)(up + (size_t)uid * 8) = *(uint4*)t;
  }
}

// ---- standalone MFMA GEMM: C = A*B^T + bias, fp32 out (gi) ----
__global__ __launch_bounds__(256) void k_gemm0(const u16* __restrict__ A, const u16* __restrict__ Bw,
                                               const float* __restrict__ bias, int N, int K, int nrt,
                                               float* __restrict__ outC, int Mstore) {
  __shared__ u16 As[128 * 64];
  __shared__ u16 Bs[128 * 64];
  int bid = blockIdx.x;
  int rt = bid % nrt, ct = bid / nrt;
  int m0 = rt * 128, n0 = ct * 128;
  int tid = threadIdx.x;
  int lane = tid & 63, wid = tid >> 6;
  int wr = wid >> 1, wc = wid & 1;
  f32x4 z = {0.f, 0.f, 0.f, 0.f};
  f32x4 acc[4][4];
#pragma unroll
  for (int i = 0; i < 4; ++i)
#pragma unroll
    for (int j = 0; j < 4; ++j) acc[i][j] = z;

  int nkt = K >> 6;
  for (int kt = 0; kt < nkt; ++kt) {
    __syncthreads();
#pragma unroll
    for (int it = 0; it < 4; ++it) {
      int idx = it * 256 + tid;
      int row = idx >> 3;
      int kch = idx & 7;
      int sch = kch ^ (row & 7);
      *(uint4*)(&As[row * 64 + kch * 8]) =
          *(const uint4*)(A + (size_t)(m0 + row) * K + kt * 64 + sch * 8);
      *(uint4*)(&Bs[row * 64 + kch * 8]) =
          *(const uint4*)(Bw + (size_t)(n0 + row) * K + kt * 64 + sch * 8);
    }
    __syncthreads();
#pragma unroll
    for (int kk = 0; kk < 2; ++kk) {
      bf16x8 af[4], bf[4];
#pragma unroll
      for (int i = 0; i < 4; ++i) {
        int row = wr * 64 + i * 16 + (lane & 15);
        int c = kk * 4 + (lane >> 4);
        af[i] = *(const bf16x8*)(&As[row * 64 + ((c ^ (row & 7)) * 8)]);
      }
#pragma unroll
      for (int j = 0; j < 4; ++j) {
        int row = wc * 64 + j * 16 + (lane & 15);
        int c = kk * 4 + (lane >> 4);
        bf[j] = *(const bf16x8*)(&Bs[row * 64 + ((c ^ (row & 7)) * 8)]);
      }
#pragma unroll
      for (int i = 0; i < 4; ++i)
#pragma unroll
        for (int j = 0; j < 4; ++j)
          acc[i][j] = __builtin_amdgcn_mfma_f32_16x16x32_bf16(af[i], bf[j], acc[i][j], 0, 0, 0);
    }
  }
#pragma unroll
  for (int i = 0; i < 4; ++i) {
    int mb = m0 + wr * 64 + i * 16 + ((lane >> 4) << 2);
#pragma unroll
    for (int j = 0; j < 4; ++j) {
      int n = n0 + wc * 64 + j * 16 + (lane & 15);
      float bb = bias[n];
#pragma unroll
      for (int r = 0; r < 4; ++r) {
        int m = mb + r;
        if (m < Mstore) outC[(size_t)m * N + n] = acc[i][j][r] + bb;
      }
    }
  }
}

// ================= mega-kernel =================
struct RecurSM {
  u16 hb[32 * 512];
  u16 wls[3 * 1024 * 8];
  float ghl[6][32][16];
  float gil[2][3][32][16];
  float hloc[32][16];
  float sloc[32][16];
  u16 hps[32][16];
  u16 sps[32][16];
};
struct GemmSM {
  u16 As[128 * 64];
  u16 Bs[128 * 64];
};
union MegaSM {
  RecurSM r;
  GemmSM g;
};

__device__ __forceinline__ f32x4 mm16_lds(const u16* hb, const u16* bl, int lane, int rt) {
  f32x4 a0 = {0.f, 0.f, 0.f, 0.f}, a1 = {0.f, 0.f, 0.f, 0.f};
  int row = rt * 16 + (lane & 15);
  int cb = lane >> 4;
#pragma unroll
  for (int ks = 0; ks < 16; ks += 2) {
    int c0 = ks * 4 + cb, c1 = c0 + 4;
    bf16x8 av0 = *(const bf16x8*)(&hb[row * 512 + ((c0 ^ (row & 7)) * 8)]);
    bf16x8 bv0 = *(const bf16x8*)(&bl[(ks * 64 + lane) * 8]);
    bf16x8 av1 = *(const bf16x8*)(&hb[row * 512 + ((c1 ^ (row & 7)) * 8)]);
    bf16x8 bv1 = *(const bf16x8*)(&bl[((ks + 1) * 64 + lane) * 8]);
    a0 = __builtin_amdgcn_mfma_f32_16x16x32_bf16(av0, bv0, a0, 0, 0, 0);
    a1 = __builtin_amdgcn_mfma_f32_16x16x32_bf16(av1, bv1, a1, 0, 0, 0);
  }
  return a0 + a1;
}

__device__ __forceinline__ f32x4 mm16g(const u16* hb, const u16* bp, int lane, int rt) {
  f32x4 acc = {0.f, 0.f, 0.f, 0.f};
#pragma unroll
  for (int ks = 0; ks < 16; ++ks) {
    int row = rt * 16 + (lane & 15);
    int c = ks * 4 + (lane >> 4);
    bf16x8 a = *(const bf16x8*)(&hb[row * 512 + ((c ^ (row & 7)) * 8)]);
    bf16x8 b = *(const bf16x8*)(bp + (size_t)(ks * 64 + lane) * 8);
    acc = __builtin_amdgcn_mfma_f32_16x16x32_bf16(a, b, acc, 0, 0, 0);
  }
  return acc;
}

// ---- one 128x128 logits tile + fused lse partials; A (WHb) pre-swizzled ----
__device__ __forceinline__ void gemm_tile(u16* As, u16* Bs, const u16* __restrict__ A,
                                          const u16* __restrict__ Bw,
                                          const float* __restrict__ bias,
                                          int rt, int ct, float2* __restrict__ parts, int tid) {
  int m0 = rt * 128, n0 = ct * 128;
  int lane = tid & 63, wid = tid >> 6;
  int wr = wid >> 1, wc = wid & 1;  // 4x2 waves: 32 rows x 64 cols each
  f32x4 z = {0.f, 0.f, 0.f, 0.f};
  f32x4 acc[2][4];
#pragma unroll
  for (int i = 0; i < 2; ++i)
#pragma unroll
    for (int j = 0; j < 4; ++j) acc[i][j] = z;

  for (int kt = 0; kt < 8; ++kt) {
    __syncthreads();
#pragma unroll
    for (int it = 0; it < 2; ++it) {
      int idx = it * 512 + tid;
      int row = idx >> 3, kch = idx & 7;
      *(uint4*)(&As[row * 64 + kch * 8]) =
          *(const uint4*)(A + (size_t)(m0 + row) * 512 + kt * 64 + kch * 8);
      int sch = kch ^ (row & 7);
      *(uint4*)(&Bs[row * 64 + kch * 8]) =
          *(const uint4*)(Bw + (size_t)(n0 + row) * 512 + kt * 64 + sch * 8);
    }
    __syncthreads();
#pragma unroll
    for (int kk = 0; kk < 2; ++kk) {
      bf16x8 af[2], bf[4];
#pragma unroll
      for (int i = 0; i < 2; ++i) {
        int row = wr * 32 + i * 16 + (lane & 15);
        int c = kk * 4 + (lane >> 4);
        af[i] = *(const bf16x8*)(&As[row * 64 + ((c ^ (row & 7)) * 8)]);
      }
#pragma unroll
      for (int j = 0; j < 4; ++j) {
        int row = wc * 64 + j * 16 + (lane & 15);
        int c = kk * 4 + (lane >> 4);
        bf[j] = *(const bf16x8*)(&Bs[row * 64 + ((c ^ (row & 7)) * 8)]);
      }
#pragma unroll
      for (int i = 0; i < 2; ++i)
#pragma unroll
        for (int j = 0; j < 4; ++j)
          acc[i][j] = __builtin_amdgcn_mfma_f32_16x16x32_bf16(af[i], bf[j], acc[i][j], 0, 0, 0);
    }
  }
  float bb[4];
#pragma unroll
  for (int j = 0; j < 4; ++j) bb[j] = bias[n0 + wc * 64 + j * 16 + (lane & 15)];
  int chunk = ct * 2 + wc;
#pragma unroll
  for (int i = 0; i < 2; ++i) {
#pragma unroll
    for (int r = 0; r < 4; ++r) {
      float l0 = acc[i][0][r] + bb[0], l1 = acc[i][1][r] + bb[1];
      float l2 = acc[i][2][r] + bb[2], l3 = acc[i][3][r] + bb[3];
      float mx = fmaxf(fmaxf(l0, l1), fmaxf(l2, l3));
#pragma unroll
      for (int d = 1; d < 16; d <<= 1) mx = fmaxf(mx, __shfl_xor(mx, d));
      float s = __expf(l0 - mx) + __expf(l1 - mx) + __expf(l2 - mx) + __expf(l3 - mx);
#pragma unroll
      for (int d = 1; d < 16; d <<= 1) s += __shfl_xor(s, d);
      if ((lane & 15) == 0) {
        int m = m0 + wr * 32 + i * 16 + ((lane >> 4) << 2) + r;
        parts[(size_t)m * 512 + chunk] = make_float2(mx, s);
      }
    }
  }
}

__global__ __launch_bounds__(512) void k_mega(
    const float* __restrict__ gi, const u16* __restrict__ packHH, const u16* __restrict__ packIS,
    const u16* __restrict__ packHS, const float* __restrict__ bhh_w, const float* __restrict__ bih_s,
    const float* __restrict__ bhh_s, const int* __restrict__ targets, const int* __restrict__ flags,
    const float* __restrict__ sent, u64* __restrict__ hpub, u64* __restrict__ spub,
    float* __restrict__ whf, u16* __restrict__ whb, int* __restrict__ arr, int* __restrict__ ctr,
    int* __restrict__ hflg, u16* __restrict__ outw16, const float* __restrict__ outw,
    const float* __restrict__ outb, float2* __restrict__ parts) {
  __shared__ MegaSM sm;
  const int tid = threadIdx.x;
  int* steps = ctr + 32;

  if (blockIdx.x >= NWG) {
    // ---------- ct-major logits-GEMM worker: owned columns, rt-outer ----------
    const int w = blockIdx.x - NWG;  // 0..127
    const int nown = (w < 122) ? 2 : 1;
    // phase 0: owner-convert owned OutW panels f32->bf16 (sole consumer = this block)
#pragma unroll
    for (int p = 0; p < 2; ++p) {
      if (p < nown) {
        int ct = w + p * NWORK;
        const float* src = outw + (size_t)ct * 65536;
        u16* dst = outw16 + (size_t)ct * 65536;
        for (int it = 0; it < 32; ++it) {
          int e = it * 512 + tid;
          float4 v = *(const float4*)(src + (size_t)e * 4);
          u16 t[4] = {f2b(v.x), f2b(v.y), f2b(v.z), f2b(v.w)};
          *(uint2*)(dst + (size_t)e * 4) = *(uint2*)t;
        }
      }
    }
    __syncthreads();  // drain converts (vmcnt) before consuming via same-XCD L2
    // phase 1: gated rt-outer sweep
    for (int rt = 0; rt < 16; ++rt) {
      if (tid == 0) {
        int need = 4 * rt + 4;
        if (need > T_) need = T_;
        // relaxed spin (no per-poll cache invalidate), one acquire after success
        while (__hip_atomic_load(steps, __ATOMIC_RELAXED, __HIP_MEMORY_SCOPE_AGENT) < need)
          __builtin_amdgcn_s_sleep(64);
        (void)__hip_atomic_load(steps, __ATOMIC_ACQUIRE, __HIP_MEMORY_SCOPE_AGENT);
      }
      for (int p = 0; p < nown; ++p)
        gemm_tile(sm.g.As, sm.g.Bs, whb, outw16, outb, rt, w + p * NWORK, parts, tid);
      __syncthreads();
    }
    return;
  }

  // ---------- recurrence role ----------
  const int lane = tid & 63;
  const int wid = tid >> 6;
  const int gate = wid >> 1;
  const int rt = wid & 1;
  const int g = blockIdx.x;
  const int b_ = tid >> 4, hl = tid & 15;
  const int n_ = g * 16 + hl;

  {
    const uint4* src = (const uint4*)packHH;
    uint4* dst = (uint4*)sm.r.wls;
    for (int lin = tid; lin < 3072; lin += 512) {
      int which = lin >> 10, off = lin & 1023;
      dst[lin] = src[(size_t)(which * 32 + g) * 1024 + off];
    }
  }
  {
    float v = sent[(size_t)b_ * 512 + n_];
    sm.r.hloc[b_][hl] = v;
    sm.r.sloc[b_][hl] = v;
  }
  if (wid >= 6) {
    int lid = tid - 384;
    const float* base = gi + (size_t)g * 16;
#pragma unroll
    for (int q = 0; q < 3; ++q) {
      int fid = q * 128 + lid;
      int ga = fid >> 7, rem = fid & 127;
      int b = rem >> 2, h4 = (rem & 3) << 2;
      *(float4*)&sm.r.gil[0][ga][b][h4] = *(const float4*)(base + (size_t)b * 1536 + ga * 512 + h4);
    }
  }
  const float bw_r = bhh_w[n_], bw_z = bhh_w[512 + n_], bw_n = bhh_w[1024 + n_];
  __syncthreads();

  int ph = 0;   // EOS-path central-barrier phase counter
  int scur = 0;
  for (int t = 0; t < T_; ++t) {
    const int cur = t & 1, nxt = cur ^ 1;
    // distributed barrier: wait all WGs finished step t-1 (flags >= t); no RMWs
    if (wid == 0) {
      for (;;) {
        int f = (lane < 32)
            ? __hip_atomic_load(&hflg[lane * 16], __ATOMIC_RELAXED, __HIP_MEMORY_SCOPE_AGENT)
            : 0x7fffffff;
        if (__all(f >= t)) break;
        __builtin_amdgcn_s_sleep(1);
      }
      if (g == 0 && lane == 0)
        __hip_atomic_store(steps, t, __ATOMIC_RELEASE, __HIP_MEMORY_SCOPE_AGENT);
    }
    __syncthreads();
    {
      const u64* src = hpub + cur * 4096;
      u64* d = (u64*)sm.r.hb;
      for (int idx = tid; idx < 4096; idx += 512)
        d[idx] = __hip_atomic_load(&src[idx], __ATOMIC_RELAXED, __HIP_MEMORY_SCOPE_AGENT);
    }
    __syncthreads();
    if (wid < 6) {
      f32x4 acc = mm16_lds(sm.r.hb, sm.r.wls + gate * 8192, lane, rt);
      int bb = rt * 16 + ((lane >> 4) << 2);
      int cl = lane & 15;
#pragma unroll
      for (int r4 = 0; r4 < 4; ++r4) sm.r.ghl[gate][bb + r4][cl] = acc[r4];
    } else if (t + 1 < T_) {
      int lid = tid - 384;
      const float* base = gi + (size_t)(t + 1) * 32 * 1536 + g * 16;
#pragma unroll
      for (int q = 0; q < 3; ++q) {
        int fid = q * 128 + lid;
        int ga = fid >> 7, rem = fid & 127;
        int b = rem >> 2, h4 = (rem & 3) << 2;
        *(float4*)&sm.r.gil[nxt][ga][b][h4] =
            *(const float4*)(base + (size_t)b * 1536 + ga * 512 + h4);
      }
    }
    __syncthreads();
    {
      int rrow = t * 32 + b_;
      float r_ = sigm(sm.r.gil[cur][0][b_][hl] + sm.r.ghl[0][b_][hl] + bw_r);
      float z_ = sigm(sm.r.gil[cur][1][b_][hl] + sm.r.ghl[1][b_][hl] + bw_z);
      float nn = tanhf(sm.r.gil[cur][2][b_][hl] + r_ * (sm.r.ghl[2][b_][hl] + bw_n));
      float hold = sm.r.hloc[b_][hl];
      float hnew = (1.f - z_) * nn + z_ * hold;
      sm.r.hloc[b_][hl] = hnew;
      sm.r.hps[b_][hl] = f2b(hnew);
      whf[(size_t)rrow * 512 + n_] = hnew;
    }
    __syncthreads();
    if (tid < 128) {  // publish h slice -> Hpub[nxt]
      int b = tid >> 2, j = tid & 3, q = j >> 1, half = j & 1;
      u64 v = *(const u64*)&sm.r.hps[b][q * 8 + half * 4];
      int slot = (2 * g + q) ^ (b & 7);
      __hip_atomic_store(&hpub[nxt * 4096 + b * 128 + slot * 2 + half], v,
                         __ATOMIC_RELAXED, __HIP_MEMORY_SCOPE_AGENT);
    } else if (tid < 256) {  // publish WHb slice (pre-swizzled) for logits GEMM
      int l = tid - 128;
      int b = l >> 2, j = l & 3, q = j >> 1, half = j & 1;
      u64 v = *(const u64*)&sm.r.hps[b][q * 8 + half * 4];
      int slot = (2 * g + q) ^ (b & 7);
      __hip_atomic_store((u64*)whb + (size_t)(t * 32 + b) * 128 + slot * 2 + half, v,
                         __ATOMIC_RELAXED, __HIP_MEMORY_SCOPE_AGENT);
    }

    if (!flags[t]) {
      __syncthreads();  // drain publish stores (vmcnt) before flag store
      if (tid == 0)
        __hip_atomic_store(&hflg[g * 16], t + 1, __ATOMIC_RELAXED, __HIP_MEMORY_SCOPE_AGENT);
    } else {  // rare EOS path: sentence GRU + masked merge (central barriers, flag at end)
      fbar(arr, ph, tid); ++ph;  // all normal publishes done
      {
        const u64* src = hpub + nxt * 4096;
        u64* d = (u64*)sm.r.hb;
        for (int idx = tid; idx < 4096; idx += 512)
          d[idx] = __hip_atomic_load(&src[idx], __ATOMIC_RELAXED, __HIP_MEMORY_SCOPE_AGENT);
      }
      fbar(arr, ph, tid); ++ph;  // all staged before anyone republishes
      f32x4 ax = {0.f, 0.f, 0.f, 0.f};
      if (wid < 6) ax = mm16g(sm.r.hb, packIS + (size_t)(gate * 32 + g) * 8192, lane, rt);
      __syncthreads();
      {
        const u64* src = spub + scur * 4096;
        u64* d = (u64*)sm.r.hb;
        for (int idx = tid; idx < 4096; idx += 512)
          d[idx] = __hip_atomic_load(&src[idx], __ATOMIC_RELAXED, __HIP_MEMORY_SCOPE_AGENT);
      }
      __syncthreads();
      if (wid < 6) {
        f32x4 ah = mm16g(sm.r.hb, packHS + (size_t)(gate * 32 + g) * 8192, lane, rt);
        int bb = rt * 16 + ((lane >> 4) << 2);
        int cl = lane & 15;
#pragma unroll
        for (int r4 = 0; r4 < 4; ++r4) {
          sm.r.ghl[gate][bb + r4][cl] = ax[r4];
          sm.r.ghl[3 + gate][bb + r4][cl] = ah[r4];
        }
      }
      __syncthreads();
      {
        float r_ = sigm(sm.r.ghl[0][b_][hl] + bih_s[n_] + sm.r.ghl[3][b_][hl] + bhh_s[n_]);
        float z_ = sigm(sm.r.ghl[1][b_][hl] + bih_s[512 + n_] + sm.r.ghl[4][b_][hl] + bhh_s[512 + n_]);
        float nn = tanhf(sm.r.ghl[2][b_][hl] + bih_s[1024 + n_] +
                         r_ * (sm.r.ghl[5][b_][hl] + bhh_s[1024 + n_]));
        float hs = sm.r.sloc[b_][hl];
        float tmpv = (1.f - z_) * nn + z_ * hs;
        int m = (targets[b_ * 64 + t + 1] == 1);
        float hw = sm.r.hloc[b_][hl];
        float hw2 = m ? tmpv : hw;
        float hs2 = m ? tmpv : hs;
        sm.r.hloc[b_][hl] = hw2;
        sm.r.sloc[b_][hl] = hs2;
        sm.r.hps[b_][hl] = f2b(hw2);
        sm.r.sps[b_][hl] = f2b(hs2);
      }
      __syncthreads();
      if (tid < 128) {
        int b = tid >> 2, j = tid & 3, q = j >> 1, half = j & 1;
        int slot = (2 * g + q) ^ (b & 7);
        u64 v = *(const u64*)&sm.r.hps[b][q * 8 + half * 4];
        __hip_atomic_store(&hpub[nxt * 4096 + b * 128 + slot * 2 + half], v,
                           __ATOMIC_RELAXED, __HIP_MEMORY_SCOPE_AGENT);
        u64 w2 = *(const u64*)&sm.r.sps[b][q * 8 + half * 4];
        __hip_atomic_store(&spub[(scur ^ 1) * 4096 + b * 128 + slot * 2 + half], w2,
                           __ATOMIC_RELAXED, __HIP_MEMORY_SCOPE_AGENT);
      }
      scur ^= 1;
      __syncthreads();  // drain republish before flag store
      if (tid == 0)
        __hip_atomic_store(&hflg[g * 16], t + 1, __ATOMIC_RELAXED, __HIP_MEMORY_SCOPE_AGENT);
    }
  }
  // final: g0 waits for everyone's last flag, releases steps=63 for worker tail
  if (g == 0 && wid == 0) {
    for (;;) {
      int f = (lane < 32)
          ? __hip_atomic_load(&hflg[lane * 16], __ATOMIC_RELAXED, __HIP_MEMORY_SCOPE_AGENT)
          : 0x7fffffff;
      if (__all(f >= T_)) break;
      __builtin_amdgcn_s_sleep(1);
    }
    if (lane == 0)
      __hip_atomic_store(steps, T_, __ATOMIC_RELEASE, __HIP_MEMORY_SCOPE_AGENT);
  }
}

// ================= fused epilogue: lse + rowloss + sum (one block per t) =================
__global__ __launch_bounds__(512) void k_final(const float2* __restrict__ parts,
                                               const float* __restrict__ whf,
                                               const float* __restrict__ outw,
                                               const float* __restrict__ outb,
                                               const int* __restrict__ targets,
                                               const int* __restrict__ tlen,
                                               float* __restrict__ out) {
  const int t = blockIdx.x;  // 0..62
  const int tid = threadIdx.x;
  const int wv = tid >> 6, lane = tid & 63;
  __shared__ float wsum[8];
  float lsum = 0.f;
#pragma unroll
  for (int q = 0; q < 4; ++q) {
    int b = wv * 4 + q;
    int r = t * 32 + b;
    // lse over 500 chunks
    float m = -3.0e38f, s = 0.f;
    for (int c = lane; c < 500; c += 64) {
      float2 p = parts[(size_t)r * 512 + c];
      float nm = fmaxf(m, p.x);
      s = s * __expf(m - nm) + p.y * __expf(p.x - nm);
      m = nm;
    }
#pragma unroll
    for (int d = 1; d < 64; d <<= 1) {
      float om = __shfl_xor(m, d), os = __shfl_xor(s, d);
      float nm = fmaxf(m, om);
      s = s * __expf(m - nm) + os * __expf(om - nm);
      m = nm;
    }
    float lse = m + __logf(s);
    // target logit (exact fp32)
    int nw = targets[b * 64 + t + 1];
    const float* hv = whf + (size_t)r * 512;
    const float* wvp = outw + (size_t)nw * 512;
    int k = lane * 8;
    float4 a0 = *(const float4*)(hv + k);
    float4 w0 = *(const float4*)(wvp + k);
    float4 a1 = *(const float4*)(hv + k + 4);
    float4 w1 = *(const float4*)(wvp + k + 4);
    float acc = a0.x * w0.x + a0.y * w0.y + a0.z * w0.z + a0.w * w0.w +
                a1.x * w1.x + a1.y * w1.y + a1.z * w1.z + a1.w * w1.w;
#pragma unroll
    for (int d = 1; d < 64; d <<= 1) acc += __shfl_xor(acc, d);
    if (lane == 0) {
      bool valid = tlen[b] > (t + 1);
      lsum += valid ? (lse - (acc + outb[nw])) : 0.f;
    }
  }
  if (lane == 0) wsum[wv] = lsum;
  __syncthreads();
  if (tid == 0) {
    float a = 0.f;
#pragma unroll
    for (int i = 0; i < 8; ++i) a += wsum[i];
    atomicAdd(out, a);
  }
}

extern "C" void kernel_launch(void* const* d_in, const int* in_sizes, int n_in,
                              void* d_out, int out_size, void* d_ws, size_t ws_size,
                              hipStream_t stream) {
  const int* targets = (const int*)d_in[0];
  const int* tkws    = (const int*)d_in[1];
  const float* sent  = (const float*)d_in[2];
  const int* tlen    = (const int*)d_in[3];
  const float* emb   = (const float*)d_in[4];
  const float* wihw  = (const float*)d_in[5];
  const float* whhw  = (const float*)d_in[6];
  const float* bihw  = (const float*)d_in[7];
  const float* bhhw  = (const float*)d_in[8];
  const float* wihs  = (const float*)d_in[9];
  const float* whhs  = (const float*)d_in[10];
  const float* bihs  = (const float*)d_in[11];
  const float* bhhs  = (const float*)d_in[12];
  const float* outw  = (const float*)d_in[13];
  const float* outb  = (const float*)d_in[14];
  float* out = (float*)d_out;
  char* ws = (char*)d_ws;

  u16* X       = (u16*)(ws + o_X);
  u16* Wih16   = (u16*)(ws + o_Wih);
  u16* OutW16  = (u16*)(ws + o_OutW);
  u16* PackHH  = (u16*)(ws + o_PackHH);
  u16* PackIS  = (u16*)(ws + o_PackIS);
  u16* PackHS  = (u16*)(ws + o_PackHS);
  float* GI    = (float*)(ws + o_GI);
  float* WHf   = (float*)(ws + o_WHf);
  u16* WHb     = (u16*)(ws + o_WHb);
  u64* HPUB    = (u64*)(ws + o_HPUB);
  u64* SPUB    = (u64*)(ws + o_SPUB);
  int* ARR     = (int*)(ws + o_ARR);
  int* CTR     = (int*)(ws + o_CTR);
  float2* PART = (float2*)(ws + o_PART);
  int* FLG     = (int*)(ws + o_FLG);
  int* HFLG    = (int*)(ws + o_HFLG);

  // fused prologue: gather | init(+out zero) | cvt(wih) | pack x3
  k_prep<<<dim3(4800), dim3(256), 0, stream>>>(emb, targets, tkws, X, sent, HPUB, SPUB, WHb,
                                               FLG, ARR, CTR, HFLG, wihw, Wih16,
                                               whhw, PackHH, wihs, PackIS, whhs, PackHS, out);

  // gi = X @ w_ih_w^T + b_ih_w   (M=2048 pad, N=1536, K=1024)
  k_gemm0<<<dim3(16 * 12), dim3(256), 0, stream>>>(X, Wih16, bihw, G3_, 1024, 16, GI, R_);

  // fused: recurrence (blocks 0..31) + 128 ct-major workers (owner-convert + logits GEMM)
  k_mega<<<dim3(NWG + NWORK), dim3(512), 0, stream>>>(GI, PackHH, PackIS, PackHS, bhhw, bihs, bhhs,
                                                      targets, FLG, sent, HPUB, SPUB, WHf, WHb,
                                                      ARR, CTR, HFLG, OutW16, outw, outb, PART);

  // fused epilogue: lse + rowloss + sum
  k_final<<<dim3(T_), dim3(512), 0, stream>>>(PART, WHf, outw, outb, targets, tlen, out);
}

// Round 11
// 388.358 us; speedup vs baseline: 1.0333x; 1.0333x over previous
//
#include <hip/hip_runtime.h>
#include <stdint.h>

typedef short bf16x8 __attribute__((ext_vector_type(8)));
typedef float f32x4 __attribute__((ext_vector_type(4)));
typedef unsigned short u16;
typedef unsigned long long u64;

#define B_  32
#define S_  64
#define V_  32000
#define H_  512
#define T_  63
#define R_  2016
#define RP_ 2048
#define G3_ 1536
#define NWG 32
#define NWORK 192

// ---- workspace offsets (bytes), all 1KB aligned ----
#define o_X      0ull          // X bf16 [2048][1024]
#define o_Wih    4194304ull    // w_ih_w bf16 [1536][1024]
#define o_OutW   7340032ull    // out_w bf16 [32000][512]
#define o_PackHH 40108032ull   // packed w_hh_w frags
#define o_PackIS 41680896ull   // packed w_ih_s frags
#define o_PackHS 43253760ull   // packed w_hh_s frags
#define o_GI     44826624ull   // gi fp32 [2016][1536]
#define o_WHf    57212928ull   // word_h fp32 [2016][512]
#define o_WHb    61341696ull   // word_h bf16 pre-swizzled [2048][512]
#define o_HPUB   63438848ull   // published h bf16 (chunk-swizzled) [2][4096] u64
#define o_SPUB   63504384ull   // published sent_h [2][4096] u64
#define o_ARR    63569920ull   // EOS-path arrival counters int[256]
#define o_CTR    63571968ull   // [32]=steps_done
#define o_PART   63733760ull   // partials float2 [2048][512]
#define o_FLG    72138752ull   // eos flags int[64]
#define o_HFLG   72139776ull   // per-WG step flags int[32*16] (64B apart)

__device__ __forceinline__ u16 f2b(float f) {
  unsigned u = __float_as_uint(f);
  u = (u + 0x7FFFu + ((u >> 16) & 1u)) >> 16;
  return (u16)u;
}
__device__ __forceinline__ float sigm(float x) { return 1.0f / (1.0f + __expf(-x)); }

// ---- EOS-path central barrier (rare) ----
__device__ __forceinline__ void fbar(int* arr, int ph, int tid) {
  __syncthreads();
  if (tid == 0) {
    __hip_atomic_fetch_add(&arr[ph], 1, __ATOMIC_RELAXED, __HIP_MEMORY_SCOPE_AGENT);
    while (__hip_atomic_load(&arr[ph], __ATOMIC_RELAXED, __HIP_MEMORY_SCOPE_AGENT) < NWG)
      __builtin_amdgcn_s_sleep(1);
  }
  __syncthreads();
}

// ================= fused prologue: gather | init | cvt(wih) | pack x3 | out-zero =================
__global__ __launch_bounds__(256) void k_prep(
    const float* __restrict__ emb, const int* __restrict__ tg, const int* __restrict__ tk,
    u16* __restrict__ X, const float* __restrict__ sent, u64* __restrict__ hpub,
    u64* __restrict__ spub, u16* __restrict__ whb, int* __restrict__ flg, int* __restrict__ arr,
    int* __restrict__ ctr, int* __restrict__ hflg, const float* __restrict__ wihw,
    u16* __restrict__ wih16, const float* __restrict__ whhw, u16* __restrict__ packHH,
    const float* __restrict__ wihs, u16* __restrict__ packIS, const float* __restrict__ whhs,
    u16* __restrict__ packHS, float* __restrict__ out) {
  const int bid = blockIdx.x;
  const int tid = threadIdx.x;
  if (bid < 2048) {
    // ---- gather X = [emb[kw] | emb[lw]] bf16, pad rows zero ----
    int r = bid;
    u16* xr = X + (size_t)r * 1024;
    if (r < R_) {
      int t = r >> 5, b = r & 31;
      int kw = tk[b * 64 + t + 1];
      int lw = tg[b * 64 + t];
      const float* src = (tid < 128) ? (emb + (size_t)kw * 512 + tid * 4)
                                     : (emb + (size_t)lw * 512 + (tid - 128) * 4);
      float4 v = *(const float4*)src;
      u16 o[4] = {f2b(v.x), f2b(v.y), f2b(v.z), f2b(v.w)};
      *(uint2*)(xr + tid * 4) = *(uint2*)o;
    } else {
      u16 z[4] = {0, 0, 0, 0};
      *(uint2*)(xr + tid * 4) = *(uint2*)z;
    }
  } else if (bid < 2112) {
    // ---- init: Hpub[0]/Spub[0], whb pad, flags, counters, out zero ----
    int lb = bid - 2048;
    int idx = lb * 256 + tid;  // < 16384
    whb[(size_t)R_ * 512 + idx] = 0;
    if (idx < 2048) {  // chunk (b, c): 8 bf16 at slot c^(b&7)
      int b = idx >> 6, c = idx & 63;
      const float* p = sent + (size_t)b * 512 + c * 8;
      float4 v0 = *(const float4*)p;
      float4 v1 = *(const float4*)(p + 4);
      u16 t[8] = {f2b(v0.x), f2b(v0.y), f2b(v0.z), f2b(v0.w),
                  f2b(v1.x), f2b(v1.y), f2b(v1.z), f2b(v1.w)};
      int slot = c ^ (b & 7);
      u64* d = hpub + b * 128 + slot * 2;
      d[0] = ((const u64*)t)[0];
      d[1] = ((const u64*)t)[1];
      u64* s = spub + b * 128 + slot * 2;
      s[0] = ((const u64*)t)[0];
      s[1] = ((const u64*)t)[1];
    }
    if (lb == 0 && tid < 63) {
      int f = 0;
      for (int b = 0; b < 32; ++b) f |= (tg[b * 64 + tid + 1] == 1);
      flg[tid] = f;
    }
    if (lb == 1) arr[tid] = 0;
    if (lb == 2) ctr[tid] = 0;
    if (lb == 3) hflg[tid] = 0;
    if (lb == 4) hflg[256 + tid] = 0;
    if (lb == 5 && tid == 0) out[0] = 0.f;
  } else if (bid < 3648) {
    // ---- f32 -> bf16 rowmajor convert: w_ih_w ----
    int i4 = ((bid - 2112) * 256 + tid) * 4;
    if (i4 < G3_ * 1024) {
      float4 v = *(const float4*)(wihw + i4);
      u16 t[4] = {f2b(v.x), f2b(v.y), f2b(v.z), f2b(v.w)};
      *(uint2*)(wih16 + i4) = *(uint2*)t;
    }
  } else {
    // ---- pack [1536][512] f32 weight into bf16 MFMA B-fragment order ----
    int pb = bid - 3648;  // 0..1151
    const float* w;
    u16* up;
    int lb;
    if (pb < 384) { w = whhw; up = packHH; lb = pb; }
    else if (pb < 768) { w = wihs; up = packIS; lb = pb - 384; }
    else { w = whhs; up = packHS; lb = pb - 768; }
    int uid = lb * 256 + tid;  // < 98304
    int lane = uid & 63;
    int ksct = uid >> 6;
    int ks = ksct & 15, ct = ksct >> 4;
    int nrow = ct * 16 + (lane & 15);
    int k0 = ks * 32 + (lane >> 4) * 8;
    const float* p = w + (size_t)nrow * 512 + k0;
    float4 v0 = *(const float4*)p;
    float4 v1 = *(const float4*)(p + 4);
    u16 t[8] = {f2b(v0.x), f2b(v0.y), f2b(v0.z), f2b(v0.w),
                f2b(v1.x), f2b(v1.y), f2b(v1.z), f2b(v1.w)};
    *(uint4*)(up + (size_t)uid * 8) = *(uint4*)t;
  }
}

// ---- standalone MFMA GEMM: C = A*B^T + bias, fp32 out (gi) ----
__global__ __launch_bounds__(256) void k_gemm0(const u16* __restrict__ A, const u16* __restrict__ Bw,
                                               const float* __restrict__ bias, int N, int K, int nrt,
                                               float* __restrict__ outC, int Mstore) {
  __shared__ u16 As[128 * 64];
  __shared__ u16 Bs[128 * 64];
  int bid = blockIdx.x;
  int rt = bid % nrt, ct = bid / nrt;
  int m0 = rt * 128, n0 = ct * 128;
  int tid = threadIdx.x;
  int lane = tid & 63, wid = tid >> 6;
  int wr = wid >> 1, wc = wid & 1;
  f32x4 z = {0.f, 0.f, 0.f, 0.f};
  f32x4 acc[4][4];
#pragma unroll
  for (int i = 0; i < 4; ++i)
#pragma unroll
    for (int j = 0; j < 4; ++j) acc[i][j] = z;

  int nkt = K >> 6;
  for (int kt = 0; kt < nkt; ++kt) {
    __syncthreads();
#pragma unroll
    for (int it = 0; it < 4; ++it) {
      int idx = it * 256 + tid;
      int row = idx >> 3;
      int kch = idx & 7;
      int sch = kch ^ (row & 7);
      *(uint4*)(&As[row * 64 + kch * 8]) =
          *(const uint4*)(A + (size_t)(m0 + row) * K + kt * 64 + sch * 8);
      *(uint4*)(&Bs[row * 64 + kch * 8]) =
          *(const uint4*)(Bw + (size_t)(n0 + row) * K + kt * 64 + sch * 8);
    }
    __syncthreads();
#pragma unroll
    for (int kk = 0; kk < 2; ++kk) {
      bf16x8 af[4], bf[4];
#pragma unroll
      for (int i = 0; i < 4; ++i) {
        int row = wr * 64 + i * 16 + (lane & 15);
        int c = kk * 4 + (lane >> 4);
        af[i] = *(const bf16x8*)(&As[row * 64 + ((c ^ (row & 7)) * 8)]);
      }
#pragma unroll
      for (int j = 0; j < 4; ++j) {
        int row = wc * 64 + j * 16 + (lane & 15);
        int c = kk * 4 + (lane >> 4);
        bf[j] = *(const bf16x8*)(&Bs[row * 64 + ((c ^ (row & 7)) * 8)]);
      }
#pragma unroll
      for (int i = 0; i < 4; ++i)
#pragma unroll
        for (int j = 0; j < 4; ++j)
          acc[i][j] = __builtin_amdgcn_mfma_f32_16x16x32_bf16(af[i], bf[j], acc[i][j], 0, 0, 0);
    }
  }
#pragma unroll
  for (int i = 0; i < 4; ++i) {
    int mb = m0 + wr * 64 + i * 16 + ((lane >> 4) << 2);
#pragma unroll
    for (int j = 0; j < 4; ++j) {
      int n = n0 + wc * 64 + j * 16 + (lane & 15);
      float bb = bias[n];
#pragma unroll
      for (int r = 0; r < 4; ++r) {
        int m = mb + r;
        if (m < Mstore) outC[(size_t)m * N + n] = acc[i][j][r] + bb;
      }
    }
  }
}

// ================= mega-kernel =================
struct RecurSM {
  u16 hb[32 * 512];
  u16 wls[3 * 1024 * 8];
  float ghl[6][32][16];
  float gil[2][3][32][16];
  float hloc[32][16];
  float sloc[32][16];
  u16 hps[32][16];
  u16 sps[32][16];
};
struct GemmSM {
  u16 As[128 * 64];
  u16 Bs[128 * 64];
};
union MegaSM {
  RecurSM r;
  GemmSM g;
};

__device__ __forceinline__ f32x4 mm16_lds(const u16* hb, const u16* bl, int lane, int rt) {
  f32x4 a0 = {0.f, 0.f, 0.f, 0.f}, a1 = {0.f, 0.f, 0.f, 0.f};
  int row = rt * 16 + (lane & 15);
  int cb = lane >> 4;
#pragma unroll
  for (int ks = 0; ks < 16; ks += 2) {
    int c0 = ks * 4 + cb, c1 = c0 + 4;
    bf16x8 av0 = *(const bf16x8*)(&hb[row * 512 + ((c0 ^ (row & 7)) * 8)]);
    bf16x8 bv0 = *(const bf16x8*)(&bl[(ks * 64 + lane) * 8]);
    bf16x8 av1 = *(const bf16x8*)(&hb[row * 512 + ((c1 ^ (row & 7)) * 8)]);
    bf16x8 bv1 = *(const bf16x8*)(&bl[((ks + 1) * 64 + lane) * 8]);
    a0 = __builtin_amdgcn_mfma_f32_16x16x32_bf16(av0, bv0, a0, 0, 0, 0);
    a1 = __builtin_amdgcn_mfma_f32_16x16x32_bf16(av1, bv1, a1, 0, 0, 0);
  }
  return a0 + a1;
}

__device__ __forceinline__ f32x4 mm16g(const u16* hb, const u16* bp, int lane, int rt) {
  f32x4 acc = {0.f, 0.f, 0.f, 0.f};
#pragma unroll
  for (int ks = 0; ks < 16; ++ks) {
    int row = rt * 16 + (lane & 15);
    int c = ks * 4 + (lane >> 4);
    bf16x8 a = *(const bf16x8*)(&hb[row * 512 + ((c ^ (row & 7)) * 8)]);
    bf16x8 b = *(const bf16x8*)(bp + (size_t)(ks * 64 + lane) * 8);
    acc = __builtin_amdgcn_mfma_f32_16x16x32_bf16(a, b, acc, 0, 0, 0);
  }
  return acc;
}

// ---- one 128x128 logits tile + fused lse partials; A (WHb) pre-swizzled ----
__device__ __forceinline__ void gemm_tile(u16* As, u16* Bs, const u16* __restrict__ A,
                                          const u16* __restrict__ Bw,
                                          const float* __restrict__ bias,
                                          int rt, int ct, float2* __restrict__ parts, int tid) {
  int m0 = rt * 128, n0 = ct * 128;
  int lane = tid & 63, wid = tid >> 6;
  int wr = wid >> 1, wc = wid & 1;  // 4x2 waves: 32 rows x 64 cols each
  f32x4 z = {0.f, 0.f, 0.f, 0.f};
  f32x4 acc[2][4];
#pragma unroll
  for (int i = 0; i < 2; ++i)
#pragma unroll
    for (int j = 0; j < 4; ++j) acc[i][j] = z;

  for (int kt = 0; kt < 8; ++kt) {
    __syncthreads();
#pragma unroll
    for (int it = 0; it < 2; ++it) {
      int idx = it * 512 + tid;
      int row = idx >> 3, kch = idx & 7;
      *(uint4*)(&As[row * 64 + kch * 8]) =
          *(const uint4*)(A + (size_t)(m0 + row) * 512 + kt * 64 + kch * 8);
      int sch = kch ^ (row & 7);
      *(uint4*)(&Bs[row * 64 + kch * 8]) =
          *(const uint4*)(Bw + (size_t)(n0 + row) * 512 + kt * 64 + sch * 8);
    }
    __syncthreads();
#pragma unroll
    for (int kk = 0; kk < 2; ++kk) {
      bf16x8 af[2], bf[4];
#pragma unroll
      for (int i = 0; i < 2; ++i) {
        int row = wr * 32 + i * 16 + (lane & 15);
        int c = kk * 4 + (lane >> 4);
        af[i] = *(const bf16x8*)(&As[row * 64 + ((c ^ (row & 7)) * 8)]);
      }
#pragma unroll
      for (int j = 0; j < 4; ++j) {
        int row = wc * 64 + j * 16 + (lane & 15);
        int c = kk * 4 + (lane >> 4);
        bf[j] = *(const bf16x8*)(&Bs[row * 64 + ((c ^ (row & 7)) * 8)]);
      }
#pragma unroll
      for (int i = 0; i < 2; ++i)
#pragma unroll
        for (int j = 0; j < 4; ++j)
          acc[i][j] = __builtin_amdgcn_mfma_f32_16x16x32_bf16(af[i], bf[j], acc[i][j], 0, 0, 0);
    }
  }
  float bb[4];
#pragma unroll
  for (int j = 0; j < 4; ++j) bb[j] = bias[n0 + wc * 64 + j * 16 + (lane & 15)];
  int chunk = ct * 2 + wc;
#pragma unroll
  for (int i = 0; i < 2; ++i) {
#pragma unroll
    for (int r = 0; r < 4; ++r) {
      float l0 = acc[i][0][r] + bb[0], l1 = acc[i][1][r] + bb[1];
      float l2 = acc[i][2][r] + bb[2], l3 = acc[i][3][r] + bb[3];
      float mx = fmaxf(fmaxf(l0, l1), fmaxf(l2, l3));
#pragma unroll
      for (int d = 1; d < 16; d <<= 1) mx = fmaxf(mx, __shfl_xor(mx, d));
      float s = __expf(l0 - mx) + __expf(l1 - mx) + __expf(l2 - mx) + __expf(l3 - mx);
#pragma unroll
      for (int d = 1; d < 16; d <<= 1) s += __shfl_xor(s, d);
      if ((lane & 15) == 0) {
        int m = m0 + wr * 32 + i * 16 + ((lane >> 4) << 2) + r;
        parts[(size_t)m * 512 + chunk] = make_float2(mx, s);
      }
    }
  }
}

__global__ __launch_bounds__(512) void k_mega(
    const float* __restrict__ gi, const u16* __restrict__ packHH, const u16* __restrict__ packIS,
    const u16* __restrict__ packHS, const float* __restrict__ bhh_w, const float* __restrict__ bih_s,
    const float* __restrict__ bhh_s, const int* __restrict__ targets, const int* __restrict__ flags,
    const float* __restrict__ sent, u64* __restrict__ hpub, u64* __restrict__ spub,
    float* __restrict__ whf, u16* __restrict__ whb, int* __restrict__ arr, int* __restrict__ ctr,
    int* __restrict__ hflg, u16* __restrict__ outw16, const float* __restrict__ outw,
    const float* __restrict__ outb, float2* __restrict__ parts) {
  __shared__ MegaSM sm;
  const int tid = threadIdx.x;
  int* steps = ctr + 32;

  if (blockIdx.x >= NWG) {
    // ---------- ct-major logits-GEMM worker: owned columns, rt-outer ----------
    const int w = blockIdx.x - NWG;  // 0..191
    const int nown = (w < 58) ? 2 : 1;
    // phase 0: owner-convert owned OutW panels f32->bf16 (sole consumer = this block)
#pragma unroll
    for (int p = 0; p < 2; ++p) {
      if (p < nown) {
        int ct = w + p * NWORK;
        const float* src = outw + (size_t)ct * 65536;
        u16* dst = outw16 + (size_t)ct * 65536;
        for (int it = 0; it < 32; ++it) {
          int e = it * 512 + tid;
          float4 v = *(const float4*)(src + (size_t)e * 4);
          u16 t[4] = {f2b(v.x), f2b(v.y), f2b(v.z), f2b(v.w)};
          *(uint2*)(dst + (size_t)e * 4) = *(uint2*)t;
        }
      }
    }
    __syncthreads();  // drain converts (vmcnt) before consuming via same-XCD L2
    // phase 1: gated rt-outer sweep
    for (int rt = 0; rt < 16; ++rt) {
      if (tid == 0) {
        int need = 4 * rt + 4;
        if (need > T_) need = T_;
        // relaxed spin (no per-poll cache invalidate), one acquire after success
        while (__hip_atomic_load(steps, __ATOMIC_RELAXED, __HIP_MEMORY_SCOPE_AGENT) < need)
          __builtin_amdgcn_s_sleep(64);
        (void)__hip_atomic_load(steps, __ATOMIC_ACQUIRE, __HIP_MEMORY_SCOPE_AGENT);
      }
      for (int p = 0; p < nown; ++p)
        gemm_tile(sm.g.As, sm.g.Bs, whb, outw16, outb, rt, w + p * NWORK, parts, tid);
      __syncthreads();
    }
    return;
  }

  // ---------- recurrence role ----------
  const int lane = tid & 63;
  const int wid = tid >> 6;
  const int gate = wid >> 1;
  const int rt = wid & 1;
  const int g = blockIdx.x;
  const int b_ = tid >> 4, hl = tid & 15;
  const int n_ = g * 16 + hl;

  {
    const uint4* src = (const uint4*)packHH;
    uint4* dst = (uint4*)sm.r.wls;
    for (int lin = tid; lin < 3072; lin += 512) {
      int which = lin >> 10, off = lin & 1023;
      dst[lin] = src[(size_t)(which * 32 + g) * 1024 + off];
    }
  }
  {
    float v = sent[(size_t)b_ * 512 + n_];
    sm.r.hloc[b_][hl] = v;
    sm.r.sloc[b_][hl] = v;
  }
  if (wid >= 6) {
    int lid = tid - 384;
    const float* base = gi + (size_t)g * 16;
#pragma unroll
    for (int q = 0; q < 3; ++q) {
      int fid = q * 128 + lid;
      int ga = fid >> 7, rem = fid & 127;
      int b = rem >> 2, h4 = (rem & 3) << 2;
      *(float4*)&sm.r.gil[0][ga][b][h4] = *(const float4*)(base + (size_t)b * 1536 + ga * 512 + h4);
    }
  }
  const float bw_r = bhh_w[n_], bw_z = bhh_w[512 + n_], bw_n = bhh_w[1024 + n_];
  __syncthreads();

  int ph = 0;   // EOS-path central-barrier phase counter
  int scur = 0;
  for (int t = 0; t < T_; ++t) {
    const int cur = t & 1, nxt = cur ^ 1;
    // distributed barrier: wait all WGs finished step t-1 (flags >= t); no RMWs
    if (wid == 0) {
      for (;;) {
        int f = (lane < 32)
            ? __hip_atomic_load(&hflg[lane * 16], __ATOMIC_RELAXED, __HIP_MEMORY_SCOPE_AGENT)
            : 0x7fffffff;
        if (__all(f >= t)) break;
        __builtin_amdgcn_s_sleep(1);
      }
      if (g == 0 && lane == 0)
        __hip_atomic_store(steps, t, __ATOMIC_RELEASE, __HIP_MEMORY_SCOPE_AGENT);
    }
    __syncthreads();
    {
      const u64* src = hpub + cur * 4096;
      u64* d = (u64*)sm.r.hb;
      for (int idx = tid; idx < 4096; idx += 512)
        d[idx] = __hip_atomic_load(&src[idx], __ATOMIC_RELAXED, __HIP_MEMORY_SCOPE_AGENT);
    }
    __syncthreads();
    if (wid < 6) {
      f32x4 acc = mm16_lds(sm.r.hb, sm.r.wls + gate * 8192, lane, rt);
      int bb = rt * 16 + ((lane >> 4) << 2);
      int cl = lane & 15;
#pragma unroll
      for (int r4 = 0; r4 < 4; ++r4) sm.r.ghl[gate][bb + r4][cl] = acc[r4];
    } else if (t + 1 < T_) {
      int lid = tid - 384;
      const float* base = gi + (size_t)(t + 1) * 32 * 1536 + g * 16;
#pragma unroll
      for (int q = 0; q < 3; ++q) {
        int fid = q * 128 + lid;
        int ga = fid >> 7, rem = fid & 127;
        int b = rem >> 2, h4 = (rem & 3) << 2;
        *(float4*)&sm.r.gil[nxt][ga][b][h4] =
            *(const float4*)(base + (size_t)b * 1536 + ga * 512 + h4);
      }
    }
    __syncthreads();
    {
      int rrow = t * 32 + b_;
      float r_ = sigm(sm.r.gil[cur][0][b_][hl] + sm.r.ghl[0][b_][hl] + bw_r);
      float z_ = sigm(sm.r.gil[cur][1][b_][hl] + sm.r.ghl[1][b_][hl] + bw_z);
      float nn = tanhf(sm.r.gil[cur][2][b_][hl] + r_ * (sm.r.ghl[2][b_][hl] + bw_n));
      float hold = sm.r.hloc[b_][hl];
      float hnew = (1.f - z_) * nn + z_ * hold;
      sm.r.hloc[b_][hl] = hnew;
      sm.r.hps[b_][hl] = f2b(hnew);
      whf[(size_t)rrow * 512 + n_] = hnew;
    }
    __syncthreads();
    if (tid < 128) {  // publish h slice -> Hpub[nxt]
      int b = tid >> 2, j = tid & 3, q = j >> 1, half = j & 1;
      u64 v = *(const u64*)&sm.r.hps[b][q * 8 + half * 4];
      int slot = (2 * g + q) ^ (b & 7);
      __hip_atomic_store(&hpub[nxt * 4096 + b * 128 + slot * 2 + half], v,
                         __ATOMIC_RELAXED, __HIP_MEMORY_SCOPE_AGENT);
    } else if (tid < 256) {  // publish WHb slice (pre-swizzled) for logits GEMM
      int l = tid - 128;
      int b = l >> 2, j = l & 3, q = j >> 1, half = j & 1;
      u64 v = *(const u64*)&sm.r.hps[b][q * 8 + half * 4];
      int slot = (2 * g + q) ^ (b & 7);
      __hip_atomic_store((u64*)whb + (size_t)(t * 32 + b) * 128 + slot * 2 + half, v,
                         __ATOMIC_RELAXED, __HIP_MEMORY_SCOPE_AGENT);
    }

    if (!flags[t]) {
      __syncthreads();  // drain publish stores (vmcnt) before flag store
      if (tid == 0)
        __hip_atomic_store(&hflg[g * 16], t + 1, __ATOMIC_RELAXED, __HIP_MEMORY_SCOPE_AGENT);
    } else {  // rare EOS path: sentence GRU + masked merge (central barriers, flag at end)
      fbar(arr, ph, tid); ++ph;  // all normal publishes done
      {
        const u64* src = hpub + nxt * 4096;
        u64* d = (u64*)sm.r.hb;
        for (int idx = tid; idx < 4096; idx += 512)
          d[idx] = __hip_atomic_load(&src[idx], __ATOMIC_RELAXED, __HIP_MEMORY_SCOPE_AGENT);
      }
      fbar(arr, ph, tid); ++ph;  // all staged before anyone republishes
      f32x4 ax = {0.f, 0.f, 0.f, 0.f};
      if (wid < 6) ax = mm16g(sm.r.hb, packIS + (size_t)(gate * 32 + g) * 8192, lane, rt);
      __syncthreads();
      {
        const u64* src = spub + scur * 4096;
        u64* d = (u64*)sm.r.hb;
        for (int idx = tid; idx < 4096; idx += 512)
          d[idx] = __hip_atomic_load(&src[idx], __ATOMIC_RELAXED, __HIP_MEMORY_SCOPE_AGENT);
      }
      __syncthreads();
      if (wid < 6) {
        f32x4 ah = mm16g(sm.r.hb, packHS + (size_t)(gate * 32 + g) * 8192, lane, rt);
        int bb = rt * 16 + ((lane >> 4) << 2);
        int cl = lane & 15;
#pragma unroll
        for (int r4 = 0; r4 < 4; ++r4) {
          sm.r.ghl[gate][bb + r4][cl] = ax[r4];
          sm.r.ghl[3 + gate][bb + r4][cl] = ah[r4];
        }
      }
      __syncthreads();
      {
        float r_ = sigm(sm.r.ghl[0][b_][hl] + bih_s[n_] + sm.r.ghl[3][b_][hl] + bhh_s[n_]);
        float z_ = sigm(sm.r.ghl[1][b_][hl] + bih_s[512 + n_] + sm.r.ghl[4][b_][hl] + bhh_s[512 + n_]);
        float nn = tanhf(sm.r.ghl[2][b_][hl] + bih_s[1024 + n_] +
                         r_ * (sm.r.ghl[5][b_][hl] + bhh_s[1024 + n_]));
        float hs = sm.r.sloc[b_][hl];
        float tmpv = (1.f - z_) * nn + z_ * hs;
        int m = (targets[b_ * 64 + t + 1] == 1);
        float hw = sm.r.hloc[b_][hl];
        float hw2 = m ? tmpv : hw;
        float hs2 = m ? tmpv : hs;
        sm.r.hloc[b_][hl] = hw2;
        sm.r.sloc[b_][hl] = hs2;
        sm.r.hps[b_][hl] = f2b(hw2);
        sm.r.sps[b_][hl] = f2b(hs2);
      }
      __syncthreads();
      if (tid < 128) {
        int b = tid >> 2, j = tid & 3, q = j >> 1, half = j & 1;
        int slot = (2 * g + q) ^ (b & 7);
        u64 v = *(const u64*)&sm.r.hps[b][q * 8 + half * 4];
        __hip_atomic_store(&hpub[nxt * 4096 + b * 128 + slot * 2 + half], v,
                           __ATOMIC_RELAXED, __HIP_MEMORY_SCOPE_AGENT);
        u64 w2 = *(const u64*)&sm.r.sps[b][q * 8 + half * 4];
        __hip_atomic_store(&spub[(scur ^ 1) * 4096 + b * 128 + slot * 2 + half], w2,
                           __ATOMIC_RELAXED, __HIP_MEMORY_SCOPE_AGENT);
      }
      scur ^= 1;
      __syncthreads();  // drain republish before flag store
      if (tid == 0)
        __hip_atomic_store(&hflg[g * 16], t + 1, __ATOMIC_RELAXED, __HIP_MEMORY_SCOPE_AGENT);
    }
  }
  // final: g0 waits for everyone's last flag, releases steps=63 for worker tail
  if (g == 0 && wid == 0) {
    for (;;) {
      int f = (lane < 32)
          ? __hip_atomic_load(&hflg[lane * 16], __ATOMIC_RELAXED, __HIP_MEMORY_SCOPE_AGENT)
          : 0x7fffffff;
      if (__all(f >= T_)) break;
      __builtin_amdgcn_s_sleep(1);
    }
    if (lane == 0)
      __hip_atomic_store(steps, T_, __ATOMIC_RELEASE, __HIP_MEMORY_SCOPE_AGENT);
  }
}

// ================= fused epilogue: lse + rowloss + sum (one block per t) =================
__global__ __launch_bounds__(512) void k_final(const float2* __restrict__ parts,
                                               const float* __restrict__ whf,
                                               const float* __restrict__ outw,
                                               const float* __restrict__ outb,
                                               const int* __restrict__ targets,
                                               const int* __restrict__ tlen,
                                               float* __restrict__ out) {
  const int t = blockIdx.x;  // 0..62
  const int tid = threadIdx.x;
  const int wv = tid >> 6, lane = tid & 63;
  __shared__ float wsum[8];
  float lsum = 0.f;
#pragma unroll
  for (int q = 0; q < 4; ++q) {
    int b = wv * 4 + q;
    int r = t * 32 + b;
    // lse over 500 chunks
    float m = -3.0e38f, s = 0.f;
    for (int c = lane; c < 500; c += 64) {
      float2 p = parts[(size_t)r * 512 + c];
      float nm = fmaxf(m, p.x);
      s = s * __expf(m - nm) + p.y * __expf(p.x - nm);
      m = nm;
    }
#pragma unroll
    for (int d = 1; d < 64; d <<= 1) {
      float om = __shfl_xor(m, d), os = __shfl_xor(s, d);
      float nm = fmaxf(m, om);
      s = s * __expf(m - nm) + os * __expf(om - nm);
      m = nm;
    }
    float lse = m + __logf(s);
    // target logit (exact fp32)
    int nw = targets[b * 64 + t + 1];
    const float* hv = whf + (size_t)r * 512;
    const float* wvp = outw + (size_t)nw * 512;
    int k = lane * 8;
    float4 a0 = *(const float4*)(hv + k);
    float4 w0 = *(const float4*)(wvp + k);
    float4 a1 = *(const float4*)(hv + k + 4);
    float4 w1 = *(const float4*)(wvp + k + 4);
    float acc = a0.x * w0.x + a0.y * w0.y + a0.z * w0.z + a0.w * w0.w +
                a1.x * w1.x + a1.y * w1.y + a1.z * w1.z + a1.w * w1.w;
#pragma unroll
    for (int d = 1; d < 64; d <<= 1) acc += __shfl_xor(acc, d);
    if (lane == 0) {
      bool valid = tlen[b] > (t + 1);
      lsum += valid ? (lse - (acc + outb[nw])) : 0.f;
    }
  }
  if (lane == 0) wsum[wv] = lsum;
  __syncthreads();
  if (tid == 0) {
    float a = 0.f;
#pragma unroll
    for (int i = 0; i < 8; ++i) a += wsum[i];
    atomicAdd(out, a);
  }
}

extern "C" void kernel_launch(void* const* d_in, const int* in_sizes, int n_in,
                              void* d_out, int out_size, void* d_ws, size_t ws_size,
                              hipStream_t stream) {
  const int* targets = (const int*)d_in[0];
  const int* tkws    = (const int*)d_in[1];
  const float* sent  = (const float*)d_in[2];
  const int* tlen    = (const int*)d_in[3];
  const float* emb   = (const float*)d_in[4];
  const float* wihw  = (const float*)d_in[5];
  const float* whhw  = (const float*)d_in[6];
  const float* bihw  = (const float*)d_in[7];
  const float* bhhw  = (const float*)d_in[8];
  const float* wihs  = (const float*)d_in[9];
  const float* whhs  = (const float*)d_in[10];
  const float* bihs  = (const float*)d_in[11];
  const float* bhhs  = (const float*)d_in[12];
  const float* outw  = (const float*)d_in[13];
  const float* outb  = (const float*)d_in[14];
  float* out = (float*)d_out;
  char* ws = (char*)d_ws;

  u16* X       = (u16*)(ws + o_X);
  u16* Wih16   = (u16*)(ws + o_Wih);
  u16* OutW16  = (u16*)(ws + o_OutW);
  u16* PackHH  = (u16*)(ws + o_PackHH);
  u16* PackIS  = (u16*)(ws + o_PackIS);
  u16* PackHS  = (u16*)(ws + o_PackHS);
  float* GI    = (float*)(ws + o_GI);
  float* WHf   = (float*)(ws + o_WHf);
  u16* WHb     = (u16*)(ws + o_WHb);
  u64* HPUB    = (u64*)(ws + o_HPUB);
  u64* SPUB    = (u64*)(ws + o_SPUB);
  int* ARR     = (int*)(ws + o_ARR);
  int* CTR     = (int*)(ws + o_CTR);
  float2* PART = (float2*)(ws + o_PART);
  int* FLG     = (int*)(ws + o_FLG);
  int* HFLG    = (int*)(ws + o_HFLG);

  // fused prologue: gather | init(+out zero) | cvt(wih) | pack x3
  k_prep<<<dim3(4800), dim3(256), 0, stream>>>(emb, targets, tkws, X, sent, HPUB, SPUB, WHb,
                                               FLG, ARR, CTR, HFLG, wihw, Wih16,
                                               whhw, PackHH, wihs, PackIS, whhs, PackHS, out);

  // gi = X @ w_ih_w^T + b_ih_w   (M=2048 pad, N=1536, K=1024)
  k_gemm0<<<dim3(16 * 12), dim3(256), 0, stream>>>(X, Wih16, bihw, G3_, 1024, 16, GI, R_);

  // fused: recurrence (blocks 0..31) + 192 ct-major workers (owner-convert + logits GEMM)
  k_mega<<<dim3(NWG + NWORK), dim3(512), 0, stream>>>(GI, PackHH, PackIS, PackHS, bhhw, bihs, bhhs,
                                                      targets, FLG, sent, HPUB, SPUB, WHf, WHb,
                                                      ARR, CTR, HFLG, OutW16, outw, outb, PART);

  // fused epilogue: lse + rowloss + sum
  k_final<<<dim3(T_), dim3(512), 0, stream>>>(PART, WHf, outw, outb, targets, tlen, out);
}

// Round 12
// 359.602 us; speedup vs baseline: 1.1159x; 1.0800x over previous
//
#include <hip/hip_runtime.h>
#include <stdint.h>

typedef short bf16x8 __attribute__((ext_vector_type(8)));
typedef float f32x4 __attribute__((ext_vector_type(4)));
typedef unsigned short u16;
typedef unsigned long long u64;

#define B_  32
#define S_  64
#define V_  32000
#define H_  512
#define T_  63
#define R_  2016
#define RP_ 2048
#define G3_ 1536
#define NWG 32
#define NWORK 192

// ---- workspace offsets (bytes), all 1KB aligned ----
#define o_X      0ull          // X bf16 [2048][1024]
#define o_Wih    4194304ull    // w_ih_w bf16 [1536][1024]
#define o_OutW   7340032ull    // out_w bf16 [32000][512]
#define o_PackHH 40108032ull   // packed w_hh_w frags
#define o_PackIS 41680896ull   // packed w_ih_s frags
#define o_PackHS 43253760ull   // packed w_hh_s frags
#define o_GI     44826624ull   // gi fp32 [2016][1536]
#define o_WHf    57212928ull   // word_h fp32 [2016][512]
#define o_WHb    61341696ull   // word_h bf16 pre-swizzled [2048][512]
#define o_HPUB   63438848ull   // published h bf16 (chunk-swizzled) [2][4096] u64
#define o_SPUB   63504384ull   // published sent_h [2][4096] u64
#define o_ARR    63569920ull   // EOS-path arrival counters int[256]
#define o_CTR    63571968ull   // [32]=steps_done
#define o_PART   63733760ull   // partials float2 [2048][512]
#define o_FLG    72138752ull   // eos flags int[64]
#define o_HFLG   72139776ull   // per-WG step flags int[32*16] (64B apart)

__device__ __forceinline__ u16 f2b(float f) {
  unsigned u = __float_as_uint(f);
  u = (u + 0x7FFFu + ((u >> 16) & 1u)) >> 16;
  return (u16)u;
}
__device__ __forceinline__ float sigm(float x) { return 1.0f / (1.0f + __expf(-x)); }

// ---- EOS-path central barrier (rare) ----
__device__ __forceinline__ void fbar(int* arr, int ph, int tid) {
  __syncthreads();
  if (tid == 0) {
    __hip_atomic_fetch_add(&arr[ph], 1, __ATOMIC_RELAXED, __HIP_MEMORY_SCOPE_AGENT);
    while (__hip_atomic_load(&arr[ph], __ATOMIC_RELAXED, __HIP_MEMORY_SCOPE_AGENT) < NWG)
      __builtin_amdgcn_s_sleep(1);
  }
  __syncthreads();
}

// ================= fused prologue: gather | init | cvt(wih) | pack x3 | out-zero =================
__global__ __launch_bounds__(256) void k_prep(
    const float* __restrict__ emb, const int* __restrict__ tg, const int* __restrict__ tk,
    u16* __restrict__ X, const float* __restrict__ sent, u64* __restrict__ hpub,
    u64* __restrict__ spub, u16* __restrict__ whb, int* __restrict__ flg, int* __restrict__ arr,
    int* __restrict__ ctr, int* __restrict__ hflg, const float* __restrict__ wihw,
    u16* __restrict__ wih16, const float* __restrict__ whhw, u16* __restrict__ packHH,
    const float* __restrict__ wihs, u16* __restrict__ packIS, const float* __restrict__ whhs,
    u16* __restrict__ packHS, float* __restrict__ out) {
  const int bid = blockIdx.x;
  const int tid = threadIdx.x;
  if (bid < 2048) {
    // ---- gather X = [emb[kw] | emb[lw]] bf16, pad rows zero ----
    int r = bid;
    u16* xr = X + (size_t)r * 1024;
    if (r < R_) {
      int t = r >> 5, b = r & 31;
      int kw = tk[b * 64 + t + 1];
      int lw = tg[b * 64 + t];
      const float* src = (tid < 128) ? (emb + (size_t)kw * 512 + tid * 4)
                                     : (emb + (size_t)lw * 512 + (tid - 128) * 4);
      float4 v = *(const float4*)src;
      u16 o[4] = {f2b(v.x), f2b(v.y), f2b(v.z), f2b(v.w)};
      *(uint2*)(xr + tid * 4) = *(uint2*)o;
    } else {
      u16 z[4] = {0, 0, 0, 0};
      *(uint2*)(xr + tid * 4) = *(uint2*)z;
    }
  } else if (bid < 2112) {
    // ---- init: Hpub[0]/Spub[0], whb pad, flags, counters, out zero ----
    int lb = bid - 2048;
    int idx = lb * 256 + tid;  // < 16384
    whb[(size_t)R_ * 512 + idx] = 0;
    if (idx < 2048) {  // chunk (b, c): 8 bf16 at slot c^(b&7)
      int b = idx >> 6, c = idx & 63;
      const float* p = sent + (size_t)b * 512 + c * 8;
      float4 v0 = *(const float4*)p;
      float4 v1 = *(const float4*)(p + 4);
      u16 t[8] = {f2b(v0.x), f2b(v0.y), f2b(v0.z), f2b(v0.w),
                  f2b(v1.x), f2b(v1.y), f2b(v1.z), f2b(v1.w)};
      int slot = c ^ (b & 7);
      u64* d = hpub + b * 128 + slot * 2;
      d[0] = ((const u64*)t)[0];
      d[1] = ((const u64*)t)[1];
      u64* s = spub + b * 128 + slot * 2;
      s[0] = ((const u64*)t)[0];
      s[1] = ((const u64*)t)[1];
    }
    if (lb == 0 && tid < 63) {
      int f = 0;
      for (int b = 0; b < 32; ++b) f |= (tg[b * 64 + tid + 1] == 1);
      flg[tid] = f;
    }
    if (lb == 1) arr[tid] = 0;
    if (lb == 2) ctr[tid] = 0;
    if (lb == 3) hflg[tid] = 0;
    if (lb == 4) hflg[256 + tid] = 0;
    if (lb == 5 && tid == 0) out[0] = 0.f;
  } else if (bid < 3648) {
    // ---- f32 -> bf16 rowmajor convert: w_ih_w ----
    int i4 = ((bid - 2112) * 256 + tid) * 4;
    if (i4 < G3_ * 1024) {
      float4 v = *(const float4*)(wihw + i4);
      u16 t[4] = {f2b(v.x), f2b(v.y), f2b(v.z), f2b(v.w)};
      *(uint2*)(wih16 + i4) = *(uint2*)t;
    }
  } else {
    // ---- pack [1536][512] f32 weight into bf16 MFMA B-fragment order ----
    int pb = bid - 3648;  // 0..1151
    const float* w;
    u16* up;
    int lb;
    if (pb < 384) { w = whhw; up = packHH; lb = pb; }
    else if (pb < 768) { w = wihs; up = packIS; lb = pb - 384; }
    else { w = whhs; up = packHS; lb = pb - 768; }
    int uid = lb * 256 + tid;  // < 98304
    int lane = uid & 63;
    int ksct = uid >> 6;
    int ks = ksct & 15, ct = ksct >> 4;
    int nrow = ct * 16 + (lane & 15);
    int k0 = ks * 32 + (lane >> 4) * 8;
    const float* p = w + (size_t)nrow * 512 + k0;
    float4 v0 = *(const float4*)p;
    float4 v1 = *(const float4*)(p + 4);
    u16 t[8] = {f2b(v0.x), f2b(v0.y), f2b(v0.z), f2b(v0.w),
                f2b(v1.x), f2b(v1.y), f2b(v1.z), f2b(v1.w)};
    *(uint4*)(up + (size_t)uid * 8) = *(uint4*)t;
  }
}

// ---- standalone MFMA GEMM: C = A*B^T + bias, fp32 out (gi) ----
__global__ __launch_bounds__(256) void k_gemm0(const u16* __restrict__ A, const u16* __restrict__ Bw,
                                               const float* __restrict__ bias, int N, int K, int nrt,
                                               float* __restrict__ outC, int Mstore) {
  __shared__ u16 As[128 * 64];
  __shared__ u16 Bs[128 * 64];
  int bid = blockIdx.x;
  int rt = bid % nrt, ct = bid / nrt;
  int m0 = rt * 128, n0 = ct * 128;
  int tid = threadIdx.x;
  int lane = tid & 63, wid = tid >> 6;
  int wr = wid >> 1, wc = wid & 1;
  f32x4 z = {0.f, 0.f, 0.f, 0.f};
  f32x4 acc[4][4];
#pragma unroll
  for (int i = 0; i < 4; ++i)
#pragma unroll
    for (int j = 0; j < 4; ++j) acc[i][j] = z;

  int nkt = K >> 6;
  for (int kt = 0; kt < nkt; ++kt) {
    __syncthreads();
#pragma unroll
    for (int it = 0; it < 4; ++it) {
      int idx = it * 256 + tid;
      int row = idx >> 3;
      int kch = idx & 7;
      int sch = kch ^ (row & 7);
      *(uint4*)(&As[row * 64 + kch * 8]) =
          *(const uint4*)(A + (size_t)(m0 + row) * K + kt * 64 + sch * 8);
      *(uint4*)(&Bs[row * 64 + kch * 8]) =
          *(const uint4*)(Bw + (size_t)(n0 + row) * K + kt * 64 + sch * 8);
    }
    __syncthreads();
#pragma unroll
    for (int kk = 0; kk < 2; ++kk) {
      bf16x8 af[4], bf[4];
#pragma unroll
      for (int i = 0; i < 4; ++i) {
        int row = wr * 64 + i * 16 + (lane & 15);
        int c = kk * 4 + (lane >> 4);
        af[i] = *(const bf16x8*)(&As[row * 64 + ((c ^ (row & 7)) * 8)]);
      }
#pragma unroll
      for (int j = 0; j < 4; ++j) {
        int row = wc * 64 + j * 16 + (lane & 15);
        int c = kk * 4 + (lane >> 4);
        bf[j] = *(const bf16x8*)(&Bs[row * 64 + ((c ^ (row & 7)) * 8)]);
      }
#pragma unroll
      for (int i = 0; i < 4; ++i)
#pragma unroll
        for (int j = 0; j < 4; ++j)
          acc[i][j] = __builtin_amdgcn_mfma_f32_16x16x32_bf16(af[i], bf[j], acc[i][j], 0, 0, 0);
    }
  }
#pragma unroll
  for (int i = 0; i < 4; ++i) {
    int mb = m0 + wr * 64 + i * 16 + ((lane >> 4) << 2);
#pragma unroll
    for (int j = 0; j < 4; ++j) {
      int n = n0 + wc * 64 + j * 16 + (lane & 15);
      float bb = bias[n];
#pragma unroll
      for (int r = 0; r < 4; ++r) {
        int m = mb + r;
        if (m < Mstore) outC[(size_t)m * N + n] = acc[i][j][r] + bb;
      }
    }
  }
}

// ================= mega-kernel =================
struct RecurSM {
  u16 hb[32 * 512];
  u16 wls[3 * 1024 * 8];
  float ghl[6][32][16];
  float gil[2][3][32][16];
  float hloc[32][16];
  float sloc[32][16];
  u16 hps[32][16];
  u16 sps[32][16];
};
struct GemmSM {
  u16 As[256 * 64];
  u16 Bs[128 * 64];
};
union MegaSM {
  RecurSM r;
  GemmSM g;
};

__device__ __forceinline__ f32x4 mm16_lds(const u16* hb, const u16* bl, int lane, int rt) {
  f32x4 a0 = {0.f, 0.f, 0.f, 0.f}, a1 = {0.f, 0.f, 0.f, 0.f};
  int row = rt * 16 + (lane & 15);
  int cb = lane >> 4;
#pragma unroll
  for (int ks = 0; ks < 16; ks += 2) {
    int c0 = ks * 4 + cb, c1 = c0 + 4;
    bf16x8 av0 = *(const bf16x8*)(&hb[row * 512 + ((c0 ^ (row & 7)) * 8)]);
    bf16x8 bv0 = *(const bf16x8*)(&bl[(ks * 64 + lane) * 8]);
    bf16x8 av1 = *(const bf16x8*)(&hb[row * 512 + ((c1 ^ (row & 7)) * 8)]);
    bf16x8 bv1 = *(const bf16x8*)(&bl[((ks + 1) * 64 + lane) * 8]);
    a0 = __builtin_amdgcn_mfma_f32_16x16x32_bf16(av0, bv0, a0, 0, 0, 0);
    a1 = __builtin_amdgcn_mfma_f32_16x16x32_bf16(av1, bv1, a1, 0, 0, 0);
  }
  return a0 + a1;
}

__device__ __forceinline__ f32x4 mm16g(const u16* hb, const u16* bp, int lane, int rt) {
  f32x4 acc = {0.f, 0.f, 0.f, 0.f};
#pragma unroll
  for (int ks = 0; ks < 16; ++ks) {
    int row = rt * 16 + (lane & 15);
    int c = ks * 4 + (lane >> 4);
    bf16x8 a = *(const bf16x8*)(&hb[row * 512 + ((c ^ (row & 7)) * 8)]);
    bf16x8 b = *(const bf16x8*)(bp + (size_t)(ks * 64 + lane) * 8);
    acc = __builtin_amdgcn_mfma_f32_16x16x32_bf16(a, b, acc, 0, 0, 0);
  }
  return acc;
}

// ---- one 256x128 logits tile + fused lse partials; A (WHb) pre-swizzled ----
__device__ __forceinline__ void gemm_tile(u16* As, u16* Bs, const u16* __restrict__ A,
                                          const u16* __restrict__ Bw,
                                          const float* __restrict__ bias,
                                          int rt, int ct, float2* __restrict__ parts, int tid) {
  int m0 = rt * 256, n0 = ct * 128;
  int lane = tid & 63, wid = tid >> 6;
  int wr = wid >> 1, wc = wid & 1;  // 4x2 waves: 64 rows x 64 cols each
  f32x4 z = {0.f, 0.f, 0.f, 0.f};
  f32x4 acc[4][4];
#pragma unroll
  for (int i = 0; i < 4; ++i)
#pragma unroll
    for (int j = 0; j < 4; ++j) acc[i][j] = z;

  for (int kt = 0; kt < 8; ++kt) {
    __syncthreads();
    // stage A: 256 rows x 64 cols (A already swizzled in global; linear copy)
#pragma unroll
    for (int it = 0; it < 4; ++it) {
      int idx = it * 512 + tid;
      int row = idx >> 3, kch = idx & 7;
      *(uint4*)(&As[row * 64 + kch * 8]) =
          *(const uint4*)(A + (size_t)(m0 + row) * 512 + kt * 64 + kch * 8);
    }
    // stage B: 128 rows x 64 cols, swizzle-at-stage via pre-swizzled source chunk
#pragma unroll
    for (int it = 0; it < 2; ++it) {
      int idx = it * 512 + tid;
      int row = idx >> 3, kch = idx & 7;
      int sch = kch ^ (row & 7);
      *(uint4*)(&Bs[row * 64 + kch * 8]) =
          *(const uint4*)(Bw + (size_t)(n0 + row) * 512 + kt * 64 + sch * 8);
    }
    __syncthreads();
#pragma unroll
    for (int kk = 0; kk < 2; ++kk) {
      bf16x8 af[4], bf[4];
#pragma unroll
      for (int i = 0; i < 4; ++i) {
        int row = wr * 64 + i * 16 + (lane & 15);
        int c = kk * 4 + (lane >> 4);
        af[i] = *(const bf16x8*)(&As[row * 64 + ((c ^ (row & 7)) * 8)]);
      }
#pragma unroll
      for (int j = 0; j < 4; ++j) {
        int row = wc * 64 + j * 16 + (lane & 15);
        int c = kk * 4 + (lane >> 4);
        bf[j] = *(const bf16x8*)(&Bs[row * 64 + ((c ^ (row & 7)) * 8)]);
      }
#pragma unroll
      for (int i = 0; i < 4; ++i)
#pragma unroll
        for (int j = 0; j < 4; ++j)
          acc[i][j] = __builtin_amdgcn_mfma_f32_16x16x32_bf16(af[i], bf[j], acc[i][j], 0, 0, 0);
    }
  }
  float bb[4];
#pragma unroll
  for (int j = 0; j < 4; ++j) bb[j] = bias[n0 + wc * 64 + j * 16 + (lane & 15)];
  int chunk = ct * 2 + wc;
#pragma unroll
  for (int i = 0; i < 4; ++i) {
#pragma unroll
    for (int r = 0; r < 4; ++r) {
      float l0 = acc[i][0][r] + bb[0], l1 = acc[i][1][r] + bb[1];
      float l2 = acc[i][2][r] + bb[2], l3 = acc[i][3][r] + bb[3];
      float mx = fmaxf(fmaxf(l0, l1), fmaxf(l2, l3));
#pragma unroll
      for (int d = 1; d < 16; d <<= 1) mx = fmaxf(mx, __shfl_xor(mx, d));
      float s = __expf(l0 - mx) + __expf(l1 - mx) + __expf(l2 - mx) + __expf(l3 - mx);
#pragma unroll
      for (int d = 1; d < 16; d <<= 1) s += __shfl_xor(s, d);
      if ((lane & 15) == 0) {
        int m = m0 + wr * 64 + i * 16 + ((lane >> 4) << 2) + r;
        parts[(size_t)m * 512 + chunk] = make_float2(mx, s);
      }
    }
  }
}

__global__ __launch_bounds__(512) void k_mega(
    const float* __restrict__ gi, const u16* __restrict__ packHH, const u16* __restrict__ packIS,
    const u16* __restrict__ packHS, const float* __restrict__ bhh_w, const float* __restrict__ bih_s,
    const float* __restrict__ bhh_s, const int* __restrict__ targets, const int* __restrict__ flags,
    const float* __restrict__ sent, u64* __restrict__ hpub, u64* __restrict__ spub,
    float* __restrict__ whf, u16* __restrict__ whb, int* __restrict__ arr, int* __restrict__ ctr,
    int* __restrict__ hflg, u16* __restrict__ outw16, const float* __restrict__ outw,
    const float* __restrict__ outb, float2* __restrict__ parts) {
  __shared__ MegaSM sm;
  const int tid = threadIdx.x;
  int* steps = ctr + 32;

  if (blockIdx.x >= NWG) {
    // ---------- ct-major logits-GEMM worker: owned columns, rt-outer (256-row tiles) ----------
    const int w = blockIdx.x - NWG;  // 0..191
    const int nown = (w < 58) ? 2 : 1;
    // phase 0: owner-convert owned OutW panels f32->bf16 (sole consumer = this block)
#pragma unroll
    for (int p = 0; p < 2; ++p) {
      if (p < nown) {
        int ct = w + p * NWORK;
        const float* src = outw + (size_t)ct * 65536;
        u16* dst = outw16 + (size_t)ct * 65536;
        for (int it = 0; it < 32; ++it) {
          int e = it * 512 + tid;
          float4 v = *(const float4*)(src + (size_t)e * 4);
          u16 t[4] = {f2b(v.x), f2b(v.y), f2b(v.z), f2b(v.w)};
          *(uint2*)(dst + (size_t)e * 4) = *(uint2*)t;
        }
      }
    }
    __syncthreads();  // drain converts (vmcnt) before consuming via same-XCD L2
    // phase 1: gated rt-outer sweep (8 sweeps of 256 rows)
    for (int rt = 0; rt < 8; ++rt) {
      if (tid == 0) {
        int need = 8 * rt + 8;
        if (need > T_) need = T_;
        // relaxed spin (no per-poll cache invalidate), one acquire after success
        while (__hip_atomic_load(steps, __ATOMIC_RELAXED, __HIP_MEMORY_SCOPE_AGENT) < need)
          __builtin_amdgcn_s_sleep(64);
        (void)__hip_atomic_load(steps, __ATOMIC_ACQUIRE, __HIP_MEMORY_SCOPE_AGENT);
      }
      for (int p = 0; p < nown; ++p)
        gemm_tile(sm.g.As, sm.g.Bs, whb, outw16, outb, rt, w + p * NWORK, parts, tid);
      __syncthreads();
    }
    return;
  }

  // ---------- recurrence role ----------
  const int lane = tid & 63;
  const int wid = tid >> 6;
  const int gate = wid >> 1;
  const int rt = wid & 1;
  const int g = blockIdx.x;
  const int b_ = tid >> 4, hl = tid & 15;
  const int n_ = g * 16 + hl;

  {
    const uint4* src = (const uint4*)packHH;
    uint4* dst = (uint4*)sm.r.wls;
    for (int lin = tid; lin < 3072; lin += 512) {
      int which = lin >> 10, off = lin & 1023;
      dst[lin] = src[(size_t)(which * 32 + g) * 1024 + off];
    }
  }
  {
    float v = sent[(size_t)b_ * 512 + n_];
    sm.r.hloc[b_][hl] = v;
    sm.r.sloc[b_][hl] = v;
  }
  if (wid >= 6) {
    int lid = tid - 384;
    const float* base = gi + (size_t)g * 16;
#pragma unroll
    for (int q = 0; q < 3; ++q) {
      int fid = q * 128 + lid;
      int ga = fid >> 7, rem = fid & 127;
      int b = rem >> 2, h4 = (rem & 3) << 2;
      *(float4*)&sm.r.gil[0][ga][b][h4] = *(const float4*)(base + (size_t)b * 1536 + ga * 512 + h4);
    }
  }
  const float bw_r = bhh_w[n_], bw_z = bhh_w[512 + n_], bw_n = bhh_w[1024 + n_];
  __syncthreads();

  int ph = 0;   // EOS-path central-barrier phase counter
  int scur = 0;
  for (int t = 0; t < T_; ++t) {
    const int cur = t & 1, nxt = cur ^ 1;
    // distributed barrier: wait all WGs finished step t-1 (flags >= t); no RMWs
    if (wid == 0) {
      for (;;) {
        int f = (lane < 32)
            ? __hip_atomic_load(&hflg[lane * 16], __ATOMIC_RELAXED, __HIP_MEMORY_SCOPE_AGENT)
            : 0x7fffffff;
        if (__all(f >= t)) break;
        __builtin_amdgcn_s_sleep(1);
      }
      if (g == 0 && lane == 0)
        __hip_atomic_store(steps, t, __ATOMIC_RELEASE, __HIP_MEMORY_SCOPE_AGENT);
    }
    __syncthreads();
    {
      const u64* src = hpub + cur * 4096;
      u64* d = (u64*)sm.r.hb;
      for (int idx = tid; idx < 4096; idx += 512)
        d[idx] = __hip_atomic_load(&src[idx], __ATOMIC_RELAXED, __HIP_MEMORY_SCOPE_AGENT);
    }
    __syncthreads();
    if (wid < 6) {
      f32x4 acc = mm16_lds(sm.r.hb, sm.r.wls + gate * 8192, lane, rt);
      int bb = rt * 16 + ((lane >> 4) << 2);
      int cl = lane & 15;
#pragma unroll
      for (int r4 = 0; r4 < 4; ++r4) sm.r.ghl[gate][bb + r4][cl] = acc[r4];
    } else if (t + 1 < T_) {
      int lid = tid - 384;
      const float* base = gi + (size_t)(t + 1) * 32 * 1536 + g * 16;
#pragma unroll
      for (int q = 0; q < 3; ++q) {
        int fid = q * 128 + lid;
        int ga = fid >> 7, rem = fid & 127;
        int b = rem >> 2, h4 = (rem & 3) << 2;
        *(float4*)&sm.r.gil[nxt][ga][b][h4] =
            *(const float4*)(base + (size_t)b * 1536 + ga * 512 + h4);
      }
    }
    __syncthreads();
    {
      int rrow = t * 32 + b_;
      float r_ = sigm(sm.r.gil[cur][0][b_][hl] + sm.r.ghl[0][b_][hl] + bw_r);
      float z_ = sigm(sm.r.gil[cur][1][b_][hl] + sm.r.ghl[1][b_][hl] + bw_z);
      float nn = tanhf(sm.r.gil[cur][2][b_][hl] + r_ * (sm.r.ghl[2][b_][hl] + bw_n));
      float hold = sm.r.hloc[b_][hl];
      float hnew = (1.f - z_) * nn + z_ * hold;
      sm.r.hloc[b_][hl] = hnew;
      sm.r.hps[b_][hl] = f2b(hnew);
      whf[(size_t)rrow * 512 + n_] = hnew;
    }
    __syncthreads();
    if (tid < 128) {  // publish h slice -> Hpub[nxt]
      int b = tid >> 2, j = tid & 3, q = j >> 1, half = j & 1;
      u64 v = *(const u64*)&sm.r.hps[b][q * 8 + half * 4];
      int slot = (2 * g + q) ^ (b & 7);
      __hip_atomic_store(&hpub[nxt * 4096 + b * 128 + slot * 2 + half], v,
                         __ATOMIC_RELAXED, __HIP_MEMORY_SCOPE_AGENT);
    } else if (tid < 256) {  // publish WHb slice (pre-swizzled) for logits GEMM
      int l = tid - 128;
      int b = l >> 2, j = l & 3, q = j >> 1, half = j & 1;
      u64 v = *(const u64*)&sm.r.hps[b][q * 8 + half * 4];
      int slot = (2 * g + q) ^ (b & 7);
      __hip_atomic_store((u64*)whb + (size_t)(t * 32 + b) * 128 + slot * 2 + half, v,
                         __ATOMIC_RELAXED, __HIP_MEMORY_SCOPE_AGENT);
    }

    if (!flags[t]) {
      __syncthreads();  // drain publish stores (vmcnt) before flag store
      if (tid == 0)
        __hip_atomic_store(&hflg[g * 16], t + 1, __ATOMIC_RELAXED, __HIP_MEMORY_SCOPE_AGENT);
    } else {  // rare EOS path: sentence GRU + masked merge (central barriers, flag at end)
      fbar(arr, ph, tid); ++ph;  // all normal publishes done
      {
        const u64* src = hpub + nxt * 4096;
        u64* d = (u64*)sm.r.hb;
        for (int idx = tid; idx < 4096; idx += 512)
          d[idx] = __hip_atomic_load(&src[idx], __ATOMIC_RELAXED, __HIP_MEMORY_SCOPE_AGENT);
      }
      fbar(arr, ph, tid); ++ph;  // all staged before anyone republishes
      f32x4 ax = {0.f, 0.f, 0.f, 0.f};
      if (wid < 6) ax = mm16g(sm.r.hb, packIS + (size_t)(gate * 32 + g) * 8192, lane, rt);
      __syncthreads();
      {
        const u64* src = spub + scur * 4096;
        u64* d = (u64*)sm.r.hb;
        for (int idx = tid; idx < 4096; idx += 512)
          d[idx] = __hip_atomic_load(&src[idx], __ATOMIC_RELAXED, __HIP_MEMORY_SCOPE_AGENT);
      }
      __syncthreads();
      if (wid < 6) {
        f32x4 ah = mm16g(sm.r.hb, packHS + (size_t)(gate * 32 + g) * 8192, lane, rt);
        int bb = rt * 16 + ((lane >> 4) << 2);
        int cl = lane & 15;
#pragma unroll
        for (int r4 = 0; r4 < 4; ++r4) {
          sm.r.ghl[gate][bb + r4][cl] = ax[r4];
          sm.r.ghl[3 + gate][bb + r4][cl] = ah[r4];
        }
      }
      __syncthreads();
      {
        float r_ = sigm(sm.r.ghl[0][b_][hl] + bih_s[n_] + sm.r.ghl[3][b_][hl] + bhh_s[n_]);
        float z_ = sigm(sm.r.ghl[1][b_][hl] + bih_s[512 + n_] + sm.r.ghl[4][b_][hl] + bhh_s[512 + n_]);
        float nn = tanhf(sm.r.ghl[2][b_][hl] + bih_s[1024 + n_] +
                         r_ * (sm.r.ghl[5][b_][hl] + bhh_s[1024 + n_]));
        float hs = sm.r.sloc[b_][hl];
        float tmpv = (1.f - z_) * nn + z_ * hs;
        int m = (targets[b_ * 64 + t + 1] == 1);
        float hw = sm.r.hloc[b_][hl];
        float hw2 = m ? tmpv : hw;
        float hs2 = m ? tmpv : hs;
        sm.r.hloc[b_][hl] = hw2;
        sm.r.sloc[b_][hl] = hs2;
        sm.r.hps[b_][hl] = f2b(hw2);
        sm.r.sps[b_][hl] = f2b(hs2);
      }
      __syncthreads();
      if (tid < 128) {
        int b = tid >> 2, j = tid & 3, q = j >> 1, half = j & 1;
        int slot = (2 * g + q) ^ (b & 7);
        u64 v = *(const u64*)&sm.r.hps[b][q * 8 + half * 4];
        __hip_atomic_store(&hpub[nxt * 4096 + b * 128 + slot * 2 + half], v,
                           __ATOMIC_RELAXED, __HIP_MEMORY_SCOPE_AGENT);
        u64 w2 = *(const u64*)&sm.r.sps[b][q * 8 + half * 4];
        __hip_atomic_store(&spub[(scur ^ 1) * 4096 + b * 128 + slot * 2 + half], w2,
                           __ATOMIC_RELAXED, __HIP_MEMORY_SCOPE_AGENT);
      }
      scur ^= 1;
      __syncthreads();  // drain republish before flag store
      if (tid == 0)
        __hip_atomic_store(&hflg[g * 16], t + 1, __ATOMIC_RELAXED, __HIP_MEMORY_SCOPE_AGENT);
    }
  }
  // final: g0 waits for everyone's last flag, releases steps=63 for worker tail
  if (g == 0 && wid == 0) {
    for (;;) {
      int f = (lane < 32)
          ? __hip_atomic_load(&hflg[lane * 16], __ATOMIC_RELAXED, __HIP_MEMORY_SCOPE_AGENT)
          : 0x7fffffff;
      if (__all(f >= T_)) break;
      __builtin_amdgcn_s_sleep(1);
    }
    if (lane == 0)
      __hip_atomic_store(steps, T_, __ATOMIC_RELEASE, __HIP_MEMORY_SCOPE_AGENT);
  }
}

// ================= fused epilogue: lse + rowloss + sum (one block per t) =================
__global__ __launch_bounds__(512) void k_final(const float2* __restrict__ parts,
                                               const float* __restrict__ whf,
                                               const float* __restrict__ outw,
                                               const float* __restrict__ outb,
                                               const int* __restrict__ targets,
                                               const int* __restrict__ tlen,
                                               float* __restrict__ out) {
  const int t = blockIdx.x;  // 0..62
  const int tid = threadIdx.x;
  const int wv = tid >> 6, lane = tid & 63;
  __shared__ float wsum[8];
  float lsum = 0.f;
#pragma unroll
  for (int q = 0; q < 4; ++q) {
    int b = wv * 4 + q;
    int r = t * 32 + b;
    // lse over 500 chunks
    float m = -3.0e38f, s = 0.f;
    for (int c = lane; c < 500; c += 64) {
      float2 p = parts[(size_t)r * 512 + c];
      float nm = fmaxf(m, p.x);
      s = s * __expf(m - nm) + p.y * __expf(p.x - nm);
      m = nm;
    }
#pragma unroll
    for (int d = 1; d < 64; d <<= 1) {
      float om = __shfl_xor(m, d), os = __shfl_xor(s, d);
      float nm = fmaxf(m, om);
      s = s * __expf(m - nm) + os * __expf(om - nm);
      m = nm;
    }
    float lse = m + __logf(s);
    // target logit (exact fp32)
    int nw = targets[b * 64 + t + 1];
    const float* hv = whf + (size_t)r * 512;
    const float* wvp = outw + (size_t)nw * 512;
    int k = lane * 8;
    float4 a0 = *(const float4*)(hv + k);
    float4 w0 = *(const float4*)(wvp + k);
    float4 a1 = *(const float4*)(hv + k + 4);
    float4 w1 = *(const float4*)(wvp + k + 4);
    float acc = a0.x * w0.x + a0.y * w0.y + a0.z * w0.z + a0.w * w0.w +
                a1.x * w1.x + a1.y * w1.y + a1.z * w1.z + a1.w * w1.w;
#pragma unroll
    for (int d = 1; d < 64; d <<= 1) acc += __shfl_xor(acc, d);
    if (lane == 0) {
      bool valid = tlen[b] > (t + 1);
      lsum += valid ? (lse - (acc + outb[nw])) : 0.f;
    }
  }
  if (lane == 0) wsum[wv] = lsum;
  __syncthreads();
  if (tid == 0) {
    float a = 0.f;
#pragma unroll
    for (int i = 0; i < 8; ++i) a += wsum[i];
    atomicAdd(out, a);
  }
}

extern "C" void kernel_launch(void* const* d_in, const int* in_sizes, int n_in,
                              void* d_out, int out_size, void* d_ws, size_t ws_size,
                              hipStream_t stream) {
  const int* targets = (const int*)d_in[0];
  const int* tkws    = (const int*)d_in[1];
  const float* sent  = (const float*)d_in[2];
  const int* tlen    = (const int*)d_in[3];
  const float* emb   = (const float*)d_in[4];
  const float* wihw  = (const float*)d_in[5];
  const float* whhw  = (const float*)d_in[6];
  const float* bihw  = (const float*)d_in[7];
  const float* bhhw  = (const float*)d_in[8];
  const float* wihs  = (const float*)d_in[9];
  const float* whhs  = (const float*)d_in[10];
  const float* bihs  = (const float*)d_in[11];
  const float* bhhs  = (const float*)d_in[12];
  const float* outw  = (const float*)d_in[13];
  const float* outb  = (const float*)d_in[14];
  float* out = (float*)d_out;
  char* ws = (char*)d_ws;

  u16* X       = (u16*)(ws + o_X);
  u16* Wih16   = (u16*)(ws + o_Wih);
  u16* OutW16  = (u16*)(ws + o_OutW);
  u16* PackHH  = (u16*)(ws + o_PackHH);
  u16* PackIS  = (u16*)(ws + o_PackIS);
  u16* PackHS  = (u16*)(ws + o_PackHS);
  float* GI    = (float*)(ws + o_GI);
  float* WHf   = (float*)(ws + o_WHf);
  u16* WHb     = (u16*)(ws + o_WHb);
  u64* HPUB    = (u64*)(ws + o_HPUB);
  u64* SPUB    = (u64*)(ws + o_SPUB);
  int* ARR     = (int*)(ws + o_ARR);
  int* CTR     = (int*)(ws + o_CTR);
  float2* PART = (float2*)(ws + o_PART);
  int* FLG     = (int*)(ws + o_FLG);
  int* HFLG    = (int*)(ws + o_HFLG);

  // fused prologue: gather | init(+out zero) | cvt(wih) | pack x3
  k_prep<<<dim3(4800), dim3(256), 0, stream>>>(emb, targets, tkws, X, sent, HPUB, SPUB, WHb,
                                               FLG, ARR, CTR, HFLG, wihw, Wih16,
                                               whhw, PackHH, wihs, PackIS, whhs, PackHS, out);

  // gi = X @ w_ih_w^T + b_ih_w   (M=2048 pad, N=1536, K=1024)
  k_gemm0<<<dim3(16 * 12), dim3(256), 0, stream>>>(X, Wih16, bihw, G3_, 1024, 16, GI, R_);

  // fused: recurrence (blocks 0..31) + 192 ct-major workers (owner-convert + 256-row logits tiles)
  k_mega<<<dim3(NWG + NWORK), dim3(512), 0, stream>>>(GI, PackHH, PackIS, PackHS, bhhw, bihs, bhhs,
                                                      targets, FLG, sent, HPUB, SPUB, WHf, WHb,
                                                      ARR, CTR, HFLG, OutW16, outw, outb, PART);

  // fused epilogue: lse + rowloss + sum
  k_final<<<dim3(T_), dim3(512), 0, stream>>>(PART, WHf, outw, outb, targets, tlen, out);
}